// Round 13
// baseline (434.409 us; speedup 1.0000x reference)
//
#include <hip/hip_runtime.h>
#include <math.h>

struct __attribute__((packed)) f4u { float v[4]; };  // 4B-aligned 4-float load

typedef __attribute__((ext_vector_type(8))) short bf16x8;   // 8 bf16 (4 VGPRs)
typedef __attribute__((ext_vector_type(4))) float f32x4;

#define KCH 16   // k per reduce chunk
#define NCH 256  // 4096 / KCH
#define LDF 40   // LDS fragment row stride (ushorts): 32 used + 8 pad

// ---------------- per-pixel channel sum-of-squares ----------------
__global__ __launch_bounds__(256) void sumsq_k(const float* __restrict__ lq,
                                               const float* __restrict__ refdu,
                                               float* __restrict__ S) {
  const float* src = blockIdx.z ? refdu : lq;
  const int n = blockIdx.y;
  const int h = blockIdx.x * 4 + (threadIdx.x >> 6);
  const int w = threadIdx.x & 63;
  const float* p = src + (size_t)n * 1048576 + h * 64 + w;
  float s0 = 0.f, s1 = 0.f, s2 = 0.f, s3 = 0.f;
  #pragma unroll 4
  for (int c = 0; c < 256; c += 4) {
    float x0 = p[(size_t)c * 4096];
    float x1 = p[(size_t)(c + 1) * 4096];
    float x2 = p[(size_t)(c + 2) * 4096];
    float x3 = p[(size_t)(c + 3) * 4096];
    s0 = fmaf(x0, x0, s0); s1 = fmaf(x1, x1, s1);
    s2 = fmaf(x2, x2, s2); s3 = fmaf(x3, x3, s3);
  }
  S[(blockIdx.z * 2 + n) * 4096 + h * 64 + w] = (s0 + s1) + (s2 + s3);
}

// ---------------- 3x3 box-sum -> inverse patch norms ----------------
__global__ __launch_bounds__(256) void norm_k(const float* __restrict__ S,
                                              float* __restrict__ qinv,
                                              float* __restrict__ kinv) {
  int idx = blockIdx.x * 256 + threadIdx.x;
  int pix = idx & 4095;
  int nn  = (idx >> 12) & 1;
  int arr = idx >> 13;
  int ph = pix >> 6, pw = pix & 63;
  const float* Sp = S + (arr * 2 + nn) * 4096;
  float sum = 0.f;
  #pragma unroll
  for (int dy = -1; dy <= 1; ++dy) {
    int hh = ph + dy;
    if ((unsigned)hh < 64u) {
      const float* r = Sp + hh * 64;
      #pragma unroll
      for (int dx = -1; dx <= 1; ++dx) {
        int ww = pw + dx;
        if ((unsigned)ww < 64u) sum += r[ww];
      }
    }
  }
  float inv = 1.0f / fmaxf(sqrtf(sum), 1e-12f);
  if (arr) kinv[nn * 4096 + pix] = inv;
  else     qinv[nn * 4096 + pix] = inv;
}

// ---------------- fp32 -> bf16 hi/lo split (RNE) ----------------
__global__ __launch_bounds__(256) void conv_hl(const float* __restrict__ src,
                                               unsigned short* __restrict__ hi,
                                               unsigned short* __restrict__ lo) {
  int i = (blockIdx.x * 256 + threadIdx.x) * 4;
  float4 v = *reinterpret_cast<const float4*>(src + i);
  ushort4 h, l;
  float xs[4] = {v.x, v.y, v.z, v.w};
  unsigned short hs[4], ls[4];
  #pragma unroll
  for (int j = 0; j < 4; ++j) {
    float x = xs[j];
    unsigned u = __float_as_uint(x);
    unsigned hb = (u + 0x7FFFu + ((u >> 16) & 1u)) & 0xFFFF0000u;
    hs[j] = (unsigned short)(hb >> 16);
    float r = x - __uint_as_float(hb);
    unsigned ur = __float_as_uint(r);
    ls[j] = (unsigned short)((ur + 0x7FFFu + ((ur >> 16) & 1u)) >> 16);
  }
  h = make_ushort4(hs[0], hs[1], hs[2], hs[3]);
  l = make_ushort4(ls[0], ls[1], ls[2], ls[3]);
  *reinterpret_cast<ushort4*>(hi + i) = h;
  *reinterpret_cast<ushort4*>(lo + i) = l;
}

// ---------------- MFMA GEMM: D[k][j'] = sum_c Ref[c][k]*LQ[c][C0+j'] ----------------
// grid (64, 68, nz); block 256 = 4 waves; tile 64k x 64j; wave owns 16 k-rows.
// bf16 hi/lo split: D = AhBh + AhBl + AlBh. sigma-consistent fragment layout.
// Staging roles re-bit-assigned (sh=tid&1, mp=(tid>>1)&31, g=tid>>6) so LDS
// b64 writes are 2-way (free) instead of 4-way bank-conflicted.
__global__ __launch_bounds__(256) void gemm_mfma(const unsigned short* __restrict__ Ah,
                                                 const unsigned short* __restrict__ Al,
                                                 const unsigned short* __restrict__ Bh,
                                                 const unsigned short* __restrict__ Bl,
                                                 float* __restrict__ Dbase,
                                                 int ldD, int C0, long long dstride) {
  __shared__ unsigned short LAh[64 * LDF], LAl[64 * LDF];
  __shared__ unsigned short LBh[64 * LDF], LBl[64 * LDF];
  const int tid = threadIdx.x;
  const int nz = blockIdx.z;
  const int k0 = blockIdx.x * 64;
  const int dcol0 = blockIdx.y * 64;
  const int jq0 = C0 + dcol0;
  float* D = Dbase + (size_t)nz * dstride;

  const bool oob = (jq0 < 0) || (jq0 + 64 > 4096);

  if (!oob) {
    const unsigned short* Ahb = Ah + (size_t)nz * 1048576;
    const unsigned short* Alb = Al + (size_t)nz * 1048576;
    const unsigned short* Bhb = Bh + (size_t)nz * 1048576;
    const unsigned short* Blb = Bl + (size_t)nz * 1048576;

    // staging role: (mp, g, sh) — conflict-avoiding bit assignment
    const int sh = tid & 1;
    const int mp = (tid >> 1) & 31;
    const int g  = tid >> 6;
    const int rowb = 8 * g + 4 * sh;
    const int colA = k0 + 2 * mp;
    const int colB = jq0 + 2 * mp;
    const int sIdx = (2 * mp) * LDF + g * 8 + sh * 4;

    // compute role
    const int wv = tid >> 6;
    const int lane = tid & 63;
    const int lm = lane & 15;
    const int lg = lane >> 4;
    const int offA = (wv * 16 + lm) * LDF + lg * 8;

    f32x4 acc[4];
    #pragma unroll
    for (int t = 0; t < 4; ++t) acc[t] = (f32x4){0.f, 0.f, 0.f, 0.f};

    for (int ct = 0; ct < 256; ct += 32) {
      __syncthreads();
      // ---- stage: 4 arrays x (4 u32 loads -> 2 ushort4 LDS writes) ----
      {
        const size_t r0 = (size_t)(ct + rowb) * 4096;
        unsigned a0 = *reinterpret_cast<const unsigned*>(Ahb + r0 + colA);
        unsigned a1 = *reinterpret_cast<const unsigned*>(Ahb + r0 + 4096 + colA);
        unsigned a2 = *reinterpret_cast<const unsigned*>(Ahb + r0 + 8192 + colA);
        unsigned a3 = *reinterpret_cast<const unsigned*>(Ahb + r0 + 12288 + colA);
        *reinterpret_cast<ushort4*>(&LAh[sIdx]) =
            make_ushort4(a0 & 0xffff, a1 & 0xffff, a2 & 0xffff, a3 & 0xffff);
        *reinterpret_cast<ushort4*>(&LAh[sIdx + LDF]) =
            make_ushort4(a0 >> 16, a1 >> 16, a2 >> 16, a3 >> 16);
        unsigned c0 = *reinterpret_cast<const unsigned*>(Alb + r0 + colA);
        unsigned c1 = *reinterpret_cast<const unsigned*>(Alb + r0 + 4096 + colA);
        unsigned c2 = *reinterpret_cast<const unsigned*>(Alb + r0 + 8192 + colA);
        unsigned c3 = *reinterpret_cast<const unsigned*>(Alb + r0 + 12288 + colA);
        *reinterpret_cast<ushort4*>(&LAl[sIdx]) =
            make_ushort4(c0 & 0xffff, c1 & 0xffff, c2 & 0xffff, c3 & 0xffff);
        *reinterpret_cast<ushort4*>(&LAl[sIdx + LDF]) =
            make_ushort4(c0 >> 16, c1 >> 16, c2 >> 16, c3 >> 16);
        unsigned b0 = *reinterpret_cast<const unsigned*>(Bhb + r0 + colB);
        unsigned b1 = *reinterpret_cast<const unsigned*>(Bhb + r0 + 4096 + colB);
        unsigned b2 = *reinterpret_cast<const unsigned*>(Bhb + r0 + 8192 + colB);
        unsigned b3 = *reinterpret_cast<const unsigned*>(Bhb + r0 + 12288 + colB);
        *reinterpret_cast<ushort4*>(&LBh[sIdx]) =
            make_ushort4(b0 & 0xffff, b1 & 0xffff, b2 & 0xffff, b3 & 0xffff);
        *reinterpret_cast<ushort4*>(&LBh[sIdx + LDF]) =
            make_ushort4(b0 >> 16, b1 >> 16, b2 >> 16, b3 >> 16);
        unsigned d0 = *reinterpret_cast<const unsigned*>(Blb + r0 + colB);
        unsigned d1 = *reinterpret_cast<const unsigned*>(Blb + r0 + 4096 + colB);
        unsigned d2 = *reinterpret_cast<const unsigned*>(Blb + r0 + 8192 + colB);
        unsigned d3 = *reinterpret_cast<const unsigned*>(Blb + r0 + 12288 + colB);
        *reinterpret_cast<ushort4*>(&LBl[sIdx]) =
            make_ushort4(d0 & 0xffff, d1 & 0xffff, d2 & 0xffff, d3 & 0xffff);
        *reinterpret_cast<ushort4*>(&LBl[sIdx + LDF]) =
            make_ushort4(d0 >> 16, d1 >> 16, d2 >> 16, d3 >> 16);
      }
      __syncthreads();
      // ---- fragments + MFMA ----
      bf16x8 a_h = *reinterpret_cast<const bf16x8*>(&LAh[offA]);
      bf16x8 a_l = *reinterpret_cast<const bf16x8*>(&LAl[offA]);
      #pragma unroll
      for (int t = 0; t < 4; ++t) {
        const int offB = (t * 16 + lm) * LDF + lg * 8;
        bf16x8 b_h = *reinterpret_cast<const bf16x8*>(&LBh[offB]);
        bf16x8 b_l = *reinterpret_cast<const bf16x8*>(&LBl[offB]);
        acc[t] = __builtin_amdgcn_mfma_f32_16x16x32_bf16(a_h, b_h, acc[t], 0, 0, 0);
        acc[t] = __builtin_amdgcn_mfma_f32_16x16x32_bf16(a_h, b_l, acc[t], 0, 0, 0);
        acc[t] = __builtin_amdgcn_mfma_f32_16x16x32_bf16(a_l, b_h, acc[t], 0, 0, 0);
      }
    }
    // epilogue: row = k0 + wv*16 + lg*4 + r, col = dcol0 + t*16 + lm
    #pragma unroll
    for (int t = 0; t < 4; ++t) {
      #pragma unroll
      for (int r = 0; r < 4; ++r) {
        D[(size_t)(k0 + wv * 16 + lg * 4 + r) * ldD + dcol0 + t * 16 + lm] = acc[t][r];
      }
    }
  } else {
    // zero-fill the 64x64 halo block
    const int row = tid & 63;
    const int cs = (tid >> 6) * 16;
    float* Dp = D + (size_t)(k0 + row) * ldD + dcol0 + cs;
    #pragma unroll
    for (int j = 0; j < 4; ++j)
      *reinterpret_cast<float4*>(Dp + j * 4) = make_float4(0.f, 0.f, 0.f, 0.f);
  }
}

// ---------------- fused 9-tap DIAGONAL reduce + max/argmax, 8 q per thread ----------------
__global__ __launch_bounds__(256) void reduce_max8(const float* __restrict__ Dbase,
                                                   int ldD, int C0, int Q0,
                                                   const float* __restrict__ kinv,
                                                   float* __restrict__ chunkv,
                                                   int* __restrict__ chunki,
                                                   int n0, long long dstride) {
  __shared__ float sk[KCH];
  const int n = n0 + blockIdx.z;
  const float* D = Dbase + (size_t)blockIdx.z * (size_t)dstride;
  const int k0 = blockIdx.y * KCH;
  const int kh = k0 >> 6;
  const int kwb = k0 & 63;
  if (threadIdx.x < KCH) sk[threadIdx.x] = kinv[n * 4096 + k0 + threadIdx.x];
  __syncthreads();
  const int q0 = Q0 + (blockIdx.x * 256 + threadIdx.x) * 8;
  const int qh = q0 >> 6;
  const int qw0 = q0 & 63;
  const bool up = (kh > 0) && (qh > 0);
  const bool dn = (kh < 63) && (qh < 63);
  const bool lf_ok = qw0 > 0;
  const bool rt_ok = qw0 < 56;
  float best[8]; int bidx[8];
  #pragma unroll
  for (int i = 0; i < 8; ++i) { best[i] = -INFINITY; bidx[i] = k0; }
  const float* Dq = D + (q0 - C0);
  const int step = ldD + 1;
  #pragma unroll 2
  for (int kk = 0; kk < KCH; ++kk) {
    const int kw = kwb + kk;
    const float* P = Dq + (size_t)(k0 + kk) * ldD;
    float r[8];
    {
      float4 c0 = *reinterpret_cast<const float4*>(P);
      float4 c1 = *reinterpret_cast<const float4*>(P + 4);
      r[0]=c0.x; r[1]=c0.y; r[2]=c0.z; r[3]=c0.w; r[4]=c1.x; r[5]=c1.y; r[6]=c1.z; r[7]=c1.w;
    }
    if (up) {
      float4 c0 = *reinterpret_cast<const float4*>(P - 64 * step);
      float4 c1 = *reinterpret_cast<const float4*>(P - 64 * step + 4);
      r[0]+=c0.x; r[1]+=c0.y; r[2]+=c0.z; r[3]+=c0.w; r[4]+=c1.x; r[5]+=c1.y; r[6]+=c1.z; r[7]+=c1.w;
    }
    if (dn) {
      float4 c0 = *reinterpret_cast<const float4*>(P + 64 * step);
      float4 c1 = *reinterpret_cast<const float4*>(P + 64 * step + 4);
      r[0]+=c0.x; r[1]+=c0.y; r[2]+=c0.z; r[3]+=c0.w; r[4]+=c1.x; r[5]+=c1.y; r[6]+=c1.z; r[7]+=c1.w;
    }
    if (kw > 0) {
      #pragma unroll
      for (int t = 0; t < 3; ++t) {
        if (t == 1 && !up) continue;
        if (t == 2 && !dn) continue;
        const int off = (t == 0) ? -step : (t == 1 ? -65 * step : 63 * step);
        f4u b0 = *reinterpret_cast<const f4u*>(P + off);
        f4u b1 = *reinterpret_cast<const f4u*>(P + off + 4);
        r[0] += lf_ok ? b0.v[0] : 0.f; r[1]+=b0.v[1]; r[2]+=b0.v[2]; r[3]+=b0.v[3];
        r[4]+=b1.v[0]; r[5]+=b1.v[1]; r[6]+=b1.v[2]; r[7]+=b1.v[3];
      }
    }
    if (kw < 63) {
      #pragma unroll
      for (int t = 0; t < 3; ++t) {
        if (t == 1 && !up) continue;
        if (t == 2 && !dn) continue;
        const int off = (t == 0) ? step : (t == 1 ? -63 * step : 65 * step);
        f4u b0 = *reinterpret_cast<const f4u*>(P + off);
        f4u b1 = *reinterpret_cast<const f4u*>(P + off + 4);
        r[0]+=b0.v[0]; r[1]+=b0.v[1]; r[2]+=b0.v[2]; r[3]+=b0.v[3];
        r[4]+=b1.v[0]; r[5]+=b1.v[1]; r[6]+=b1.v[2]; r[7] += rt_ok ? b1.v[3] : 0.f;
      }
    }
    const float s = sk[kk];
    const int k = k0 + kk;
    #pragma unroll
    for (int i = 0; i < 8; ++i) {
      float v = r[i] * s;
      if (v > best[i]) { best[i] = v; bidx[i] = k; }
    }
  }
  const int ob = (n * NCH + blockIdx.y) * 4096 + q0;
  *reinterpret_cast<float4*>(chunkv + ob)     = make_float4(best[0], best[1], best[2], best[3]);
  *reinterpret_cast<float4*>(chunkv + ob + 4) = make_float4(best[4], best[5], best[6], best[7]);
  *reinterpret_cast<int4*>(chunki + ob)     = make_int4(bidx[0], bidx[1], bidx[2], bidx[3]);
  *reinterpret_cast<int4*>(chunki + ob + 4) = make_int4(bidx[4], bidx[5], bidx[6], bidx[7]);
}

// ---------------- combine chunks ----------------
__global__ __launch_bounds__(256) void combine_k(const float* __restrict__ chunkv,
                                                 const int* __restrict__ chunki,
                                                 const float* __restrict__ qinv,
                                                 float* __restrict__ out_sa,
                                                 int* __restrict__ maxidx, int nch) {
  int t = blockIdx.x * 256 + threadIdx.x;
  int n = t >> 12, q = t & 4095;
  float best = -INFINITY;
  int bi = 0;
  for (int ch = 0; ch < nch; ++ch) {
    int ii = (n * nch + ch) * 4096 + q;
    float v = chunkv[ii];
    int ix = chunki[ii];
    if (v > best) { best = v; bi = ix; }
  }
  maxidx[t] = bi;
  out_sa[t] = best * qinv[t];
}

// ---------------- fp32 GEMM (stripe fallback only) ----------------
__global__ __launch_bounds__(256) void gemm_d(const float* __restrict__ Abase,
                                              const float* __restrict__ Bbase,
                                              float* __restrict__ Dbase,
                                              int ldD, int C0, long long dstride) {
  __shared__ __align__(16) float As[2][8][128];
  __shared__ __align__(16) float Bs[2][8][128];
  const int tid = threadIdx.x;
  const int nz = blockIdx.z;
  const int k0 = blockIdx.x * 128;
  const int j0 = blockIdx.y * 128;
  const float* A = Abase + (size_t)nz * 1048576;
  const float* B = Bbase + (size_t)nz * 1048576;
  float* D = Dbase + (size_t)nz * dstride;
  const int ty = tid >> 4, tx = tid & 15, lr = tid >> 5, lc = (tid & 31) << 2;
  float acc[8][8];
  #pragma unroll
  for (int i = 0; i < 8; ++i)
    #pragma unroll
    for (int j = 0; j < 8; ++j) acc[i][j] = 0.f;
  const bool oob = (C0 + j0 < 0) || (C0 + j0 + 128 > 4096);
  if (!oob) {
    const float* Ap = A + k0 + lc;
    const float* Bp = B + (C0 + j0) + lc;
    float4 av = *reinterpret_cast<const float4*>(Ap + (size_t)lr * 4096);
    float4 bv = *reinterpret_cast<const float4*>(Bp + (size_t)lr * 4096);
    *reinterpret_cast<float4*>(&As[0][lr][lc]) = av;
    *reinterpret_cast<float4*>(&Bs[0][lr][lc]) = bv;
    for (int ct = 0; ct < 256; ct += 8) {
      const int buf = (ct >> 3) & 1;
      __syncthreads();
      if (ct + 8 < 256) {
        av = *reinterpret_cast<const float4*>(Ap + (size_t)(ct + 8 + lr) * 4096);
        bv = *reinterpret_cast<const float4*>(Bp + (size_t)(ct + 8 + lr) * 4096);
      }
      #pragma unroll
      for (int kc = 0; kc < 8; ++kc) {
        float a[8], b[8];
        *reinterpret_cast<float4*>(&a[0]) = *reinterpret_cast<const float4*>(&As[buf][kc][ty * 4]);
        *reinterpret_cast<float4*>(&a[4]) = *reinterpret_cast<const float4*>(&As[buf][kc][64 + ty * 4]);
        *reinterpret_cast<float4*>(&b[0]) = *reinterpret_cast<const float4*>(&Bs[buf][kc][tx * 4]);
        *reinterpret_cast<float4*>(&b[4]) = *reinterpret_cast<const float4*>(&Bs[buf][kc][64 + tx * 4]);
        #pragma unroll
        for (int i = 0; i < 8; ++i)
          #pragma unroll
          for (int j = 0; j < 8; ++j)
            acc[i][j] = fmaf(a[i], b[j], acc[i][j]);
      }
      if (ct + 8 < 256) {
        *reinterpret_cast<float4*>(&As[buf ^ 1][lr][lc]) = av;
        *reinterpret_cast<float4*>(&Bs[buf ^ 1][lr][lc]) = bv;
      }
    }
  }
  #pragma unroll
  for (int half = 0; half < 2; ++half)
    #pragma unroll
    for (int i = 0; i < 4; ++i) {
      float* Dp = D + (size_t)(k0 + half * 64 + ty * 4 + i) * ldD + j0;
      *reinterpret_cast<float4*>(Dp + tx * 4)      = *reinterpret_cast<const float4*>(&acc[half * 4 + i][0]);
      *reinterpret_cast<float4*>(Dp + 64 + tx * 4) = *reinterpret_cast<const float4*>(&acc[half * 4 + i][4]);
    }
}

// ---------------- tex0: LDS-staged gather, 4 channels interleaved ----------------
__global__ __launch_bounds__(256) void tex0_lds(const float* __restrict__ ref,
                                                const int* __restrict__ maxidx,
                                                float* __restrict__ outp) {
  __shared__ __align__(16) float4 L[4096];
  const int cq = blockIdx.x;
  const int n  = blockIdx.y;
  const int half = blockIdx.z;
  const int tid = threadIdx.x;
  const float* p0 = ref + (((size_t)n * 256 + cq * 4) << 12);
  for (int i = 0; i < 16; ++i) {
    int px = i * 256 + tid;
    L[px] = make_float4(p0[px], p0[px + 4096], p0[px + 8192], p0[px + 12288]);
  }
  __syncthreads();
  const int* mi = maxidx + n * 4096;
  float* ob = outp + (((size_t)n * 256 + cq * 4) << 12);
  for (int i = 0; i < 8; ++i) {
    int px = half * 2048 + i * 256 + tid;
    int y = px >> 6, x = px & 63;
    float ax = 0.f, ay = 0.f, az = 0.f, aw = 0.f;
    #pragma unroll
    for (int a = -1; a <= 1; ++a) {
      int jh = y + a;
      if ((unsigned)jh < 64u) {
        #pragma unroll
        for (int b = -1; b <= 1; ++b) {
          int jw = x + b;
          if ((unsigned)jw < 64u) {
            int m = mi[jh * 64 + jw];
            int rh = (m >> 6) - a;
            int cx = (m & 63) - b;
            if ((unsigned)rh < 64u && (unsigned)cx < 64u) {
              float4 v = L[rh * 64 + cx];
              ax += v.x; ay += v.y; az += v.z; aw += v.w;
            }
          }
        }
      }
    }
    ob[px]         = ax * (1.f / 9.f);
    ob[px + 4096]  = ay * (1.f / 9.f);
    ob[px + 8192]  = az * (1.f / 9.f);
    ob[px + 12288] = aw * (1.f / 9.f);
  }
}

// ---------------- tex1: LDS-staged gather, one 128x128 plane ----------------
__global__ __launch_bounds__(256) void tex1_lds(const float* __restrict__ ref,
                                                const int* __restrict__ maxidx,
                                                float* __restrict__ outp) {
  __shared__ __align__(16) float Lf[16384];
  const int c = blockIdx.x;
  const int n = blockIdx.y;
  const int half = blockIdx.z;
  const int tid = threadIdx.x;
  const float* p0 = ref + (((size_t)n * 128 + c) << 14);
  float4* L4 = (float4*)Lf;
  const float4* g4 = (const float4*)p0;
  for (int i = 0; i < 16; ++i) {
    int g = i * 256 + tid;
    L4[g] = g4[g];
  }
  __syncthreads();
  const int* mi = maxidx + n * 4096;
  float* ob = outp + (((size_t)n * 128 + c) << 14);
  for (int i = 0; i < 16; ++i) {
    int pp = half * 4096 + i * 256 + tid;
    int xp = pp & 63;
    int y  = pp >> 6;
    int jh0 = y >> 1;
    float a0 = 0.f, a1 = 0.f;
    #pragma unroll
    for (int a = -1; a <= 1; ++a) {
      int jh = jh0 + a;
      if ((unsigned)jh < 64u) {
        #pragma unroll
        for (int b = -1; b <= 1; ++b) {
          int jw = xp + b;
          if ((unsigned)jw < 64u) {
            int m = mi[jh * 64 + jw];
            int rh = (m >> 6) - a;
            int cx = (m & 63) - b;
            if ((unsigned)rh < 64u && (unsigned)cx < 64u) {
              int off = ((rh << 1) + (y & 1)) * 128 + (cx << 1);
              float2 v = *reinterpret_cast<const float2*>(&Lf[off]);
              a0 += v.x; a1 += v.y;
            }
          }
        }
      }
    }
    *reinterpret_cast<float2*>(&ob[y * 128 + xp * 2]) =
        make_float2(a0 * (1.f / 9.f), a1 * (1.f / 9.f));
  }
}

// ---------------- tex2: global float4 taps ----------------
__global__ __launch_bounds__(256) void tex2_k(const float* __restrict__ ref,
                                              const int* __restrict__ maxidx,
                                              float* __restrict__ outp) {
  int gid = blockIdx.x * 256 + threadIdx.x;
  const int xg = gid & 63;
  const int y  = (gid >> 6) & 255;
  const int cc = (gid >> 14) & 7;
  const int n  = gid >> 17;
  const int jh0 = y >> 2;
  const int* mi = maxidx + n * 4096;
  int offs[9];
  #pragma unroll
  for (int a = -1; a <= 1; ++a) {
    #pragma unroll
    for (int b = -1; b <= 1; ++b) {
      const int t = (a + 1) * 3 + (b + 1);
      int jh = jh0 + a, jw = xg + b;
      int off = -1;
      if ((unsigned)jh < 64u && (unsigned)jw < 64u) {
        int m = mi[jh * 64 + jw];
        int rh = (m >> 6) - jh + jh0;
        int cx = (m & 63) - jw + xg;
        if ((unsigned)rh < 64u && (unsigned)cx < 64u)
          off = ((rh << 2) + (y & 3)) * 256 + (cx << 2);
      }
      offs[t] = off;
    }
  }
  const float* rb = ref + (((size_t)n * 64 + cc * 8) << 16);
  float* ob = outp + ((((size_t)n * 64 + cc * 8) * 256 + y) << 8) + xg * 4;
  #pragma unroll
  for (int i = 0; i < 8; ++i) {
    const float* r = rb + ((size_t)i << 16);
    float4 acc = make_float4(0.f, 0.f, 0.f, 0.f);
    #pragma unroll
    for (int t = 0; t < 9; ++t) {
      if (offs[t] >= 0) {
        float4 v = *reinterpret_cast<const float4*>(r + offs[t]);
        acc.x += v.x; acc.y += v.y; acc.z += v.z; acc.w += v.w;
      }
    }
    acc.x *= (1.f / 9.f); acc.y *= (1.f / 9.f); acc.z *= (1.f / 9.f); acc.w *= (1.f / 9.f);
    *reinterpret_cast<float4*>(ob + ((size_t)i << 16)) = acc;
  }
}

// ---------------- launch ----------------
extern "C" void kernel_launch(void* const* d_in, const int* in_sizes, int n_in,
                              void* d_out, int out_size, void* d_ws, size_t ws_size,
                              hipStream_t stream) {
  const float* lq    = (const float*)d_in[0];
  const float* refdu = (const float*)d_in[1];
  const float* ref0  = (const float*)d_in[2];
  const float* ref1  = (const float*)d_in[3];
  const float* ref2  = (const float*)d_in[4];
  float* out = (float*)d_out;

  float* S      = (float*)d_ws;               // 16384
  float* qinv   = S + 16384;                  // 8192
  float* kinv   = qinv + 8192;                // 8192
  int*   maxidx = (int*)(kinv + 8192);        // 8192
  float* chunkv = (float*)(maxidx + 8192);    // 2*NCH*4096 = 2097152
  int*   chunki = (int*)(chunkv + 2097152);   // 2097152
  unsigned short* Ah = (unsigned short*)(chunki + 2097152);  // 2097152 ushorts
  unsigned short* Al = Ah + 2097152;
  unsigned short* Bh = Al + 2097152;
  unsigned short* Bl = Bh + 2097152;
  const size_t aux_bytes = (size_t)(40960 + 2097152 + 2097152) * 4 + (size_t)4 * 2097152 * 2;
  float* D = (float*)((char*)d_ws + ((aux_bytes + 255) & ~(size_t)255));

  const int ldD = 4352;                        // q' in [-128, 4224)
  const size_t Dsz = (size_t)4096 * ldD * 4;   // 71.3 MB
  const long long dstr = (long long)4096 * ldD;
  size_t avail = (ws_size > aux_bytes + 256) ? (ws_size - aux_bytes - 256) : 0;

  sumsq_k<<<dim3(16, 2, 2), 256, 0, stream>>>(lq, refdu, S);
  norm_k<<<dim3(64), 256, 0, stream>>>(S, qinv, kinv);

  if (avail >= 2 * Dsz) {
    // merged MFMA path: both batches' D resident
    conv_hl<<<dim3(2048), 256, 0, stream>>>(refdu, Ah, Al);
    conv_hl<<<dim3(2048), 256, 0, stream>>>(lq, Bh, Bl);
    gemm_mfma<<<dim3(64, 68, 2), 256, 0, stream>>>(Ah, Al, Bh, Bl, D, ldD, -128, dstr);
    reduce_max8<<<dim3(2, NCH, 2), 256, 0, stream>>>(D, ldD, -128, 0, kinv,
                                                     chunkv, chunki, 0, dstr);
  } else if (avail >= Dsz) {
    conv_hl<<<dim3(2048), 256, 0, stream>>>(refdu, Ah, Al);
    conv_hl<<<dim3(2048), 256, 0, stream>>>(lq, Bh, Bl);
    for (int n = 0; n < 2; ++n) {
      gemm_mfma<<<dim3(64, 68, 1), 256, 0, stream>>>(
          Ah + (size_t)n * 1048576, Al + (size_t)n * 1048576,
          Bh + (size_t)n * 1048576, Bl + (size_t)n * 1048576, D, ldD, -128, 0);
      reduce_max8<<<dim3(2, NCH, 1), 256, 0, stream>>>(D, ldD, -128, 0, kinv,
                                                       chunkv, chunki, n, 0);
    }
  } else {
    // stripe fallback: fp32 gemm, halved-width D
    const int Wq = 2048, ldS = Wq + 256;
    for (int n = 0; n < 2; ++n) {
      for (int Q0 = 0; Q0 < 4096; Q0 += Wq) {
        int C0 = Q0 - 128;
        gemm_d<<<dim3(32, ldS / 128, 1), 256, 0, stream>>>(
            refdu + (size_t)n * 1048576, lq + (size_t)n * 1048576, D, ldS, C0, 0);
        reduce_max8<<<dim3(Wq / 2048, NCH, 1), 256, 0, stream>>>(
            D, ldS, C0, Q0, kinv, chunkv, chunki, n, 0);
      }
    }
  }
  combine_k<<<dim3(32), 256, 0, stream>>>(chunkv, chunki, qinv, out, maxidx, NCH);

  tex0_lds<<<dim3(64, 2, 2),  256, 0, stream>>>(ref0, maxidx, out + 8192);
  tex1_lds<<<dim3(128, 2, 2), 256, 0, stream>>>(ref1, maxidx, out + 2105344);
  tex2_k<<<dim3(1024), 256, 0, stream>>>(ref2, maxidx, out + 6299648);
}

// Round 14
// 391.056 us; speedup vs baseline: 1.1109x; 1.1109x over previous
//
#include <hip/hip_runtime.h>
#include <math.h>

struct __attribute__((packed)) f4u { float v[4]; };  // 4B-aligned 4-float load

typedef __attribute__((ext_vector_type(8))) short bf16x8;   // 8 bf16 (4 VGPRs)
typedef __attribute__((ext_vector_type(4))) float f32x4;

#define KCH 16   // k per reduce chunk
#define NCH 256  // 4096 / KCH
#define LDF 36   // LDS fragment row stride (ushorts): 32 used + 4 pad (18 dwords)

// load an 8-ushort fragment via two b64 reads (rows are 8B-aligned, not 16B)
__device__ inline bf16x8 ld_frag(const unsigned short* p) {
  union { unsigned long long q[2]; bf16x8 v; } u;
  u.q[0] = *reinterpret_cast<const unsigned long long*>(p);
  u.q[1] = *reinterpret_cast<const unsigned long long*>(p + 4);
  return u.v;
}

// ---------------- per-pixel channel sum-of-squares ----------------
__global__ __launch_bounds__(256) void sumsq_k(const float* __restrict__ lq,
                                               const float* __restrict__ refdu,
                                               float* __restrict__ S) {
  const float* src = blockIdx.z ? refdu : lq;
  const int n = blockIdx.y;
  const int h = blockIdx.x * 4 + (threadIdx.x >> 6);
  const int w = threadIdx.x & 63;
  const float* p = src + (size_t)n * 1048576 + h * 64 + w;
  float s0 = 0.f, s1 = 0.f, s2 = 0.f, s3 = 0.f;
  #pragma unroll 4
  for (int c = 0; c < 256; c += 4) {
    float x0 = p[(size_t)c * 4096];
    float x1 = p[(size_t)(c + 1) * 4096];
    float x2 = p[(size_t)(c + 2) * 4096];
    float x3 = p[(size_t)(c + 3) * 4096];
    s0 = fmaf(x0, x0, s0); s1 = fmaf(x1, x1, s1);
    s2 = fmaf(x2, x2, s2); s3 = fmaf(x3, x3, s3);
  }
  S[(blockIdx.z * 2 + n) * 4096 + h * 64 + w] = (s0 + s1) + (s2 + s3);
}

// ---------------- 3x3 box-sum -> inverse patch norms ----------------
__global__ __launch_bounds__(256) void norm_k(const float* __restrict__ S,
                                              float* __restrict__ qinv,
                                              float* __restrict__ kinv) {
  int idx = blockIdx.x * 256 + threadIdx.x;
  int pix = idx & 4095;
  int nn  = (idx >> 12) & 1;
  int arr = idx >> 13;
  int ph = pix >> 6, pw = pix & 63;
  const float* Sp = S + (arr * 2 + nn) * 4096;
  float sum = 0.f;
  #pragma unroll
  for (int dy = -1; dy <= 1; ++dy) {
    int hh = ph + dy;
    if ((unsigned)hh < 64u) {
      const float* r = Sp + hh * 64;
      #pragma unroll
      for (int dx = -1; dx <= 1; ++dx) {
        int ww = pw + dx;
        if ((unsigned)ww < 64u) sum += r[ww];
      }
    }
  }
  float inv = 1.0f / fmaxf(sqrtf(sum), 1e-12f);
  if (arr) kinv[nn * 4096 + pix] = inv;
  else     qinv[nn * 4096 + pix] = inv;
}

// ---------------- fp32 -> bf16 hi/lo split (RNE) ----------------
__global__ __launch_bounds__(256) void conv_hl(const float* __restrict__ src,
                                               unsigned short* __restrict__ hi,
                                               unsigned short* __restrict__ lo) {
  int i = (blockIdx.x * 256 + threadIdx.x) * 4;
  float4 v = *reinterpret_cast<const float4*>(src + i);
  float xs[4] = {v.x, v.y, v.z, v.w};
  unsigned short hs[4], ls[4];
  #pragma unroll
  for (int j = 0; j < 4; ++j) {
    float x = xs[j];
    unsigned u = __float_as_uint(x);
    unsigned hb = (u + 0x7FFFu + ((u >> 16) & 1u)) & 0xFFFF0000u;
    hs[j] = (unsigned short)(hb >> 16);
    float r = x - __uint_as_float(hb);
    unsigned ur = __float_as_uint(r);
    ls[j] = (unsigned short)((ur + 0x7FFFu + ((ur >> 16) & 1u)) >> 16);
  }
  *reinterpret_cast<ushort4*>(hi + i) = make_ushort4(hs[0], hs[1], hs[2], hs[3]);
  *reinterpret_cast<ushort4*>(lo + i) = make_ushort4(ls[0], ls[1], ls[2], ls[3]);
}

// ---------------- MFMA GEMM: D[k][j'] = sum_c Ref[c][k]*LQ[c][C0+j'] ----------------
// grid (64, 68, nz); block 256 = 4 waves; tile 64k x 64j; wave owns 16 k-rows.
// bf16 hi/lo split: D = AhBh + AhBl + AlBh. sigma-consistent fragment layout.
// Round-12 staging roles (best global coalescing); LDF=36 makes LDS writes
// 2-way (free) and reads conflict-free (2x ds_read_b64 per fragment).
__global__ __launch_bounds__(256) void gemm_mfma(const unsigned short* __restrict__ Ah,
                                                 const unsigned short* __restrict__ Al,
                                                 const unsigned short* __restrict__ Bh,
                                                 const unsigned short* __restrict__ Bl,
                                                 float* __restrict__ Dbase,
                                                 int ldD, int C0, long long dstride) {
  __shared__ unsigned short LAh[64 * LDF], LAl[64 * LDF];
  __shared__ unsigned short LBh[64 * LDF], LBl[64 * LDF];
  const int tid = threadIdx.x;
  const int nz = blockIdx.z;
  const int k0 = blockIdx.x * 64;
  const int dcol0 = blockIdx.y * 64;
  const int jq0 = C0 + dcol0;
  float* D = Dbase + (size_t)nz * dstride;

  const bool oob = (jq0 < 0) || (jq0 + 64 > 4096);

  if (!oob) {
    const unsigned short* Ahb = Ah + (size_t)nz * 1048576;
    const unsigned short* Alb = Al + (size_t)nz * 1048576;
    const unsigned short* Bhb = Bh + (size_t)nz * 1048576;
    const unsigned short* Blb = Bl + (size_t)nz * 1048576;

    // staging role (round-12 bit assignment: best global coalescing)
    const int mp = tid & 31;
    const int g  = (tid >> 5) & 3;
    const int sh = tid >> 7;
    const int rowb = 8 * g + 4 * sh;
    const int colA = k0 + 2 * mp;
    const int colB = jq0 + 2 * mp;
    const int sIdx = (2 * mp) * LDF + g * 8 + sh * 4;

    // compute role
    const int wv = tid >> 6;
    const int lane = tid & 63;
    const int lm = lane & 15;
    const int lg = lane >> 4;
    const int offA = (wv * 16 + lm) * LDF + lg * 8;

    f32x4 acc[4];
    #pragma unroll
    for (int t = 0; t < 4; ++t) acc[t] = (f32x4){0.f, 0.f, 0.f, 0.f};

    for (int ct = 0; ct < 256; ct += 32) {
      __syncthreads();
      // ---- stage: 4 arrays x (4 u32 loads -> 2 ushort4 LDS writes) ----
      {
        const size_t r0 = (size_t)(ct + rowb) * 4096;
        unsigned a0 = *reinterpret_cast<const unsigned*>(Ahb + r0 + colA);
        unsigned a1 = *reinterpret_cast<const unsigned*>(Ahb + r0 + 4096 + colA);
        unsigned a2 = *reinterpret_cast<const unsigned*>(Ahb + r0 + 8192 + colA);
        unsigned a3 = *reinterpret_cast<const unsigned*>(Ahb + r0 + 12288 + colA);
        *reinterpret_cast<ushort4*>(&LAh[sIdx]) =
            make_ushort4(a0 & 0xffff, a1 & 0xffff, a2 & 0xffff, a3 & 0xffff);
        *reinterpret_cast<ushort4*>(&LAh[sIdx + LDF]) =
            make_ushort4(a0 >> 16, a1 >> 16, a2 >> 16, a3 >> 16);
        unsigned c0 = *reinterpret_cast<const unsigned*>(Alb + r0 + colA);
        unsigned c1 = *reinterpret_cast<const unsigned*>(Alb + r0 + 4096 + colA);
        unsigned c2 = *reinterpret_cast<const unsigned*>(Alb + r0 + 8192 + colA);
        unsigned c3 = *reinterpret_cast<const unsigned*>(Alb + r0 + 12288 + colA);
        *reinterpret_cast<ushort4*>(&LAl[sIdx]) =
            make_ushort4(c0 & 0xffff, c1 & 0xffff, c2 & 0xffff, c3 & 0xffff);
        *reinterpret_cast<ushort4*>(&LAl[sIdx + LDF]) =
            make_ushort4(c0 >> 16, c1 >> 16, c2 >> 16, c3 >> 16);
        unsigned b0 = *reinterpret_cast<const unsigned*>(Bhb + r0 + colB);
        unsigned b1 = *reinterpret_cast<const unsigned*>(Bhb + r0 + 4096 + colB);
        unsigned b2 = *reinterpret_cast<const unsigned*>(Bhb + r0 + 8192 + colB);
        unsigned b3 = *reinterpret_cast<const unsigned*>(Bhb + r0 + 12288 + colB);
        *reinterpret_cast<ushort4*>(&LBh[sIdx]) =
            make_ushort4(b0 & 0xffff, b1 & 0xffff, b2 & 0xffff, b3 & 0xffff);
        *reinterpret_cast<ushort4*>(&LBh[sIdx + LDF]) =
            make_ushort4(b0 >> 16, b1 >> 16, b2 >> 16, b3 >> 16);
        unsigned d0 = *reinterpret_cast<const unsigned*>(Blb + r0 + colB);
        unsigned d1 = *reinterpret_cast<const unsigned*>(Blb + r0 + 4096 + colB);
        unsigned d2 = *reinterpret_cast<const unsigned*>(Blb + r0 + 8192 + colB);
        unsigned d3 = *reinterpret_cast<const unsigned*>(Blb + r0 + 12288 + colB);
        *reinterpret_cast<ushort4*>(&LBl[sIdx]) =
            make_ushort4(d0 & 0xffff, d1 & 0xffff, d2 & 0xffff, d3 & 0xffff);
        *reinterpret_cast<ushort4*>(&LBl[sIdx + LDF]) =
            make_ushort4(d0 >> 16, d1 >> 16, d2 >> 16, d3 >> 16);
      }
      __syncthreads();
      // ---- fragments + MFMA ----
      bf16x8 a_h = ld_frag(&LAh[offA]);
      bf16x8 a_l = ld_frag(&LAl[offA]);
      #pragma unroll
      for (int t = 0; t < 4; ++t) {
        const int offB = (t * 16 + lm) * LDF + lg * 8;
        bf16x8 b_h = ld_frag(&LBh[offB]);
        bf16x8 b_l = ld_frag(&LBl[offB]);
        acc[t] = __builtin_amdgcn_mfma_f32_16x16x32_bf16(a_h, b_h, acc[t], 0, 0, 0);
        acc[t] = __builtin_amdgcn_mfma_f32_16x16x32_bf16(a_h, b_l, acc[t], 0, 0, 0);
        acc[t] = __builtin_amdgcn_mfma_f32_16x16x32_bf16(a_l, b_h, acc[t], 0, 0, 0);
      }
    }
    // epilogue: row = k0 + wv*16 + lg*4 + r, col = dcol0 + t*16 + lm
    #pragma unroll
    for (int t = 0; t < 4; ++t) {
      #pragma unroll
      for (int r = 0; r < 4; ++r) {
        D[(size_t)(k0 + wv * 16 + lg * 4 + r) * ldD + dcol0 + t * 16 + lm] = acc[t][r];
      }
    }
  } else {
    // zero-fill the 64x64 halo block
    const int row = tid & 63;
    const int cs = (tid >> 6) * 16;
    float* Dp = D + (size_t)(k0 + row) * ldD + dcol0 + cs;
    #pragma unroll
    for (int j = 0; j < 4; ++j)
      *reinterpret_cast<float4*>(Dp + j * 4) = make_float4(0.f, 0.f, 0.f, 0.f);
  }
}

// ---------------- fused 9-tap DIAGONAL reduce + max/argmax, 8 q per thread ----------------
__global__ __launch_bounds__(256) void reduce_max8(const float* __restrict__ Dbase,
                                                   int ldD, int C0, int Q0,
                                                   const float* __restrict__ kinv,
                                                   float* __restrict__ chunkv,
                                                   int* __restrict__ chunki,
                                                   int n0, long long dstride) {
  __shared__ float sk[KCH];
  const int n = n0 + blockIdx.z;
  const float* D = Dbase + (size_t)blockIdx.z * (size_t)dstride;
  const int k0 = blockIdx.y * KCH;
  const int kh = k0 >> 6;
  const int kwb = k0 & 63;
  if (threadIdx.x < KCH) sk[threadIdx.x] = kinv[n * 4096 + k0 + threadIdx.x];
  __syncthreads();
  const int q0 = Q0 + (blockIdx.x * 256 + threadIdx.x) * 8;
  const int qh = q0 >> 6;
  const int qw0 = q0 & 63;
  const bool up = (kh > 0) && (qh > 0);
  const bool dn = (kh < 63) && (qh < 63);
  const bool lf_ok = qw0 > 0;
  const bool rt_ok = qw0 < 56;
  float best[8]; int bidx[8];
  #pragma unroll
  for (int i = 0; i < 8; ++i) { best[i] = -INFINITY; bidx[i] = k0; }
  const float* Dq = D + (q0 - C0);
  const int step = ldD + 1;
  #pragma unroll 2
  for (int kk = 0; kk < KCH; ++kk) {
    const int kw = kwb + kk;
    const float* P = Dq + (size_t)(k0 + kk) * ldD;
    float r[8];
    {
      float4 c0 = *reinterpret_cast<const float4*>(P);
      float4 c1 = *reinterpret_cast<const float4*>(P + 4);
      r[0]=c0.x; r[1]=c0.y; r[2]=c0.z; r[3]=c0.w; r[4]=c1.x; r[5]=c1.y; r[6]=c1.z; r[7]=c1.w;
    }
    if (up) {
      float4 c0 = *reinterpret_cast<const float4*>(P - 64 * step);
      float4 c1 = *reinterpret_cast<const float4*>(P - 64 * step + 4);
      r[0]+=c0.x; r[1]+=c0.y; r[2]+=c0.z; r[3]+=c0.w; r[4]+=c1.x; r[5]+=c1.y; r[6]+=c1.z; r[7]+=c1.w;
    }
    if (dn) {
      float4 c0 = *reinterpret_cast<const float4*>(P + 64 * step);
      float4 c1 = *reinterpret_cast<const float4*>(P + 64 * step + 4);
      r[0]+=c0.x; r[1]+=c0.y; r[2]+=c0.z; r[3]+=c0.w; r[4]+=c1.x; r[5]+=c1.y; r[6]+=c1.z; r[7]+=c1.w;
    }
    if (kw > 0) {
      #pragma unroll
      for (int t = 0; t < 3; ++t) {
        if (t == 1 && !up) continue;
        if (t == 2 && !dn) continue;
        const int off = (t == 0) ? -step : (t == 1 ? -65 * step : 63 * step);
        f4u b0 = *reinterpret_cast<const f4u*>(P + off);
        f4u b1 = *reinterpret_cast<const f4u*>(P + off + 4);
        r[0] += lf_ok ? b0.v[0] : 0.f; r[1]+=b0.v[1]; r[2]+=b0.v[2]; r[3]+=b0.v[3];
        r[4]+=b1.v[0]; r[5]+=b1.v[1]; r[6]+=b1.v[2]; r[7]+=b1.v[3];
      }
    }
    if (kw < 63) {
      #pragma unroll
      for (int t = 0; t < 3; ++t) {
        if (t == 1 && !up) continue;
        if (t == 2 && !dn) continue;
        const int off = (t == 0) ? step : (t == 1 ? -63 * step : 65 * step);
        f4u b0 = *reinterpret_cast<const f4u*>(P + off);
        f4u b1 = *reinterpret_cast<const f4u*>(P + off + 4);
        r[0]+=b0.v[0]; r[1]+=b0.v[1]; r[2]+=b0.v[2]; r[3]+=b0.v[3];
        r[4]+=b1.v[0]; r[5]+=b1.v[1]; r[6]+=b1.v[2]; r[7] += rt_ok ? b1.v[3] : 0.f;
      }
    }
    const float s = sk[kk];
    const int k = k0 + kk;
    #pragma unroll
    for (int i = 0; i < 8; ++i) {
      float v = r[i] * s;
      if (v > best[i]) { best[i] = v; bidx[i] = k; }
    }
  }
  const int ob = (n * NCH + blockIdx.y) * 4096 + q0;
  *reinterpret_cast<float4*>(chunkv + ob)     = make_float4(best[0], best[1], best[2], best[3]);
  *reinterpret_cast<float4*>(chunkv + ob + 4) = make_float4(best[4], best[5], best[6], best[7]);
  *reinterpret_cast<int4*>(chunki + ob)     = make_int4(bidx[0], bidx[1], bidx[2], bidx[3]);
  *reinterpret_cast<int4*>(chunki + ob + 4) = make_int4(bidx[4], bidx[5], bidx[6], bidx[7]);
}

// ---------------- combine chunks ----------------
__global__ __launch_bounds__(256) void combine_k(const float* __restrict__ chunkv,
                                                 const int* __restrict__ chunki,
                                                 const float* __restrict__ qinv,
                                                 float* __restrict__ out_sa,
                                                 int* __restrict__ maxidx, int nch) {
  int t = blockIdx.x * 256 + threadIdx.x;
  int n = t >> 12, q = t & 4095;
  float best = -INFINITY;
  int bi = 0;
  for (int ch = 0; ch < nch; ++ch) {
    int ii = (n * nch + ch) * 4096 + q;
    float v = chunkv[ii];
    int ix = chunki[ii];
    if (v > best) { best = v; bi = ix; }
  }
  maxidx[t] = bi;
  out_sa[t] = best * qinv[t];
}

// ---------------- fp32 GEMM (stripe fallback only) ----------------
__global__ __launch_bounds__(256) void gemm_d(const float* __restrict__ Abase,
                                              const float* __restrict__ Bbase,
                                              float* __restrict__ Dbase,
                                              int ldD, int C0, long long dstride) {
  __shared__ __align__(16) float As[2][8][128];
  __shared__ __align__(16) float Bs[2][8][128];
  const int tid = threadIdx.x;
  const int nz = blockIdx.z;
  const int k0 = blockIdx.x * 128;
  const int j0 = blockIdx.y * 128;
  const float* A = Abase + (size_t)nz * 1048576;
  const float* B = Bbase + (size_t)nz * 1048576;
  float* D = Dbase + (size_t)nz * dstride;
  const int ty = tid >> 4, tx = tid & 15, lr = tid >> 5, lc = (tid & 31) << 2;
  float acc[8][8];
  #pragma unroll
  for (int i = 0; i < 8; ++i)
    #pragma unroll
    for (int j = 0; j < 8; ++j) acc[i][j] = 0.f;
  const bool oob = (C0 + j0 < 0) || (C0 + j0 + 128 > 4096);
  if (!oob) {
    const float* Ap = A + k0 + lc;
    const float* Bp = B + (C0 + j0) + lc;
    float4 av = *reinterpret_cast<const float4*>(Ap + (size_t)lr * 4096);
    float4 bv = *reinterpret_cast<const float4*>(Bp + (size_t)lr * 4096);
    *reinterpret_cast<float4*>(&As[0][lr][lc]) = av;
    *reinterpret_cast<float4*>(&Bs[0][lr][lc]) = bv;
    for (int ct = 0; ct < 256; ct += 8) {
      const int buf = (ct >> 3) & 1;
      __syncthreads();
      if (ct + 8 < 256) {
        av = *reinterpret_cast<const float4*>(Ap + (size_t)(ct + 8 + lr) * 4096);
        bv = *reinterpret_cast<const float4*>(Bp + (size_t)(ct + 8 + lr) * 4096);
      }
      #pragma unroll
      for (int kc = 0; kc < 8; ++kc) {
        float a[8], b[8];
        *reinterpret_cast<float4*>(&a[0]) = *reinterpret_cast<const float4*>(&As[buf][kc][ty * 4]);
        *reinterpret_cast<float4*>(&a[4]) = *reinterpret_cast<const float4*>(&As[buf][kc][64 + ty * 4]);
        *reinterpret_cast<float4*>(&b[0]) = *reinterpret_cast<const float4*>(&Bs[buf][kc][tx * 4]);
        *reinterpret_cast<float4*>(&b[4]) = *reinterpret_cast<const float4*>(&Bs[buf][kc][64 + tx * 4]);
        #pragma unroll
        for (int i = 0; i < 8; ++i)
          #pragma unroll
          for (int j = 0; j < 8; ++j)
            acc[i][j] = fmaf(a[i], b[j], acc[i][j]);
      }
      if (ct + 8 < 256) {
        *reinterpret_cast<float4*>(&As[buf ^ 1][lr][lc]) = av;
        *reinterpret_cast<float4*>(&Bs[buf ^ 1][lr][lc]) = bv;
      }
    }
  }
  #pragma unroll
  for (int half = 0; half < 2; ++half)
    #pragma unroll
    for (int i = 0; i < 4; ++i) {
      float* Dp = D + (size_t)(k0 + half * 64 + ty * 4 + i) * ldD + j0;
      *reinterpret_cast<float4*>(Dp + tx * 4)      = *reinterpret_cast<const float4*>(&acc[half * 4 + i][0]);
      *reinterpret_cast<float4*>(Dp + 64 + tx * 4) = *reinterpret_cast<const float4*>(&acc[half * 4 + i][4]);
    }
}

// ---------------- tex0: LDS-staged gather, 4 channels interleaved ----------------
__global__ __launch_bounds__(256) void tex0_lds(const float* __restrict__ ref,
                                                const int* __restrict__ maxidx,
                                                float* __restrict__ outp) {
  __shared__ __align__(16) float4 L[4096];
  const int cq = blockIdx.x;
  const int n  = blockIdx.y;
  const int half = blockIdx.z;
  const int tid = threadIdx.x;
  const float* p0 = ref + (((size_t)n * 256 + cq * 4) << 12);
  for (int i = 0; i < 16; ++i) {
    int px = i * 256 + tid;
    L[px] = make_float4(p0[px], p0[px + 4096], p0[px + 8192], p0[px + 12288]);
  }
  __syncthreads();
  const int* mi = maxidx + n * 4096;
  float* ob = outp + (((size_t)n * 256 + cq * 4) << 12);
  for (int i = 0; i < 8; ++i) {
    int px = half * 2048 + i * 256 + tid;
    int y = px >> 6, x = px & 63;
    float ax = 0.f, ay = 0.f, az = 0.f, aw = 0.f;
    #pragma unroll
    for (int a = -1; a <= 1; ++a) {
      int jh = y + a;
      if ((unsigned)jh < 64u) {
        #pragma unroll
        for (int b = -1; b <= 1; ++b) {
          int jw = x + b;
          if ((unsigned)jw < 64u) {
            int m = mi[jh * 64 + jw];
            int rh = (m >> 6) - a;
            int cx = (m & 63) - b;
            if ((unsigned)rh < 64u && (unsigned)cx < 64u) {
              float4 v = L[rh * 64 + cx];
              ax += v.x; ay += v.y; az += v.z; aw += v.w;
            }
          }
        }
      }
    }
    ob[px]         = ax * (1.f / 9.f);
    ob[px + 4096]  = ay * (1.f / 9.f);
    ob[px + 8192]  = az * (1.f / 9.f);
    ob[px + 12288] = aw * (1.f / 9.f);
  }
}

// ---------------- tex1: LDS-staged gather, one 128x128 plane ----------------
__global__ __launch_bounds__(256) void tex1_lds(const float* __restrict__ ref,
                                                const int* __restrict__ maxidx,
                                                float* __restrict__ outp) {
  __shared__ __align__(16) float Lf[16384];
  const int c = blockIdx.x;
  const int n = blockIdx.y;
  const int half = blockIdx.z;
  const int tid = threadIdx.x;
  const float* p0 = ref + (((size_t)n * 128 + c) << 14);
  float4* L4 = (float4*)Lf;
  const float4* g4 = (const float4*)p0;
  for (int i = 0; i < 16; ++i) {
    int g = i * 256 + tid;
    L4[g] = g4[g];
  }
  __syncthreads();
  const int* mi = maxidx + n * 4096;
  float* ob = outp + (((size_t)n * 128 + c) << 14);
  for (int i = 0; i < 16; ++i) {
    int pp = half * 4096 + i * 256 + tid;
    int xp = pp & 63;
    int y  = pp >> 6;
    int jh0 = y >> 1;
    float a0 = 0.f, a1 = 0.f;
    #pragma unroll
    for (int a = -1; a <= 1; ++a) {
      int jh = jh0 + a;
      if ((unsigned)jh < 64u) {
        #pragma unroll
        for (int b = -1; b <= 1; ++b) {
          int jw = xp + b;
          if ((unsigned)jw < 64u) {
            int m = mi[jh * 64 + jw];
            int rh = (m >> 6) - a;
            int cx = (m & 63) - b;
            if ((unsigned)rh < 64u && (unsigned)cx < 64u) {
              int off = ((rh << 1) + (y & 1)) * 128 + (cx << 1);
              float2 v = *reinterpret_cast<const float2*>(&Lf[off]);
              a0 += v.x; a1 += v.y;
            }
          }
        }
      }
    }
    *reinterpret_cast<float2*>(&ob[y * 128 + xp * 2]) =
        make_float2(a0 * (1.f / 9.f), a1 * (1.f / 9.f));
  }
}

// ---------------- tex2: global float4 taps ----------------
__global__ __launch_bounds__(256) void tex2_k(const float* __restrict__ ref,
                                              const int* __restrict__ maxidx,
                                              float* __restrict__ outp) {
  int gid = blockIdx.x * 256 + threadIdx.x;
  const int xg = gid & 63;
  const int y  = (gid >> 6) & 255;
  const int cc = (gid >> 14) & 7;
  const int n  = gid >> 17;
  const int jh0 = y >> 2;
  const int* mi = maxidx + n * 4096;
  int offs[9];
  #pragma unroll
  for (int a = -1; a <= 1; ++a) {
    #pragma unroll
    for (int b = -1; b <= 1; ++b) {
      const int t = (a + 1) * 3 + (b + 1);
      int jh = jh0 + a, jw = xg + b;
      int off = -1;
      if ((unsigned)jh < 64u && (unsigned)jw < 64u) {
        int m = mi[jh * 64 + jw];
        int rh = (m >> 6) - jh + jh0;
        int cx = (m & 63) - jw + xg;
        if ((unsigned)rh < 64u && (unsigned)cx < 64u)
          off = ((rh << 2) + (y & 3)) * 256 + (cx << 2);
      }
      offs[t] = off;
    }
  }
  const float* rb = ref + (((size_t)n * 64 + cc * 8) << 16);
  float* ob = outp + ((((size_t)n * 64 + cc * 8) * 256 + y) << 8) + xg * 4;
  #pragma unroll
  for (int i = 0; i < 8; ++i) {
    const float* r = rb + ((size_t)i << 16);
    float4 acc = make_float4(0.f, 0.f, 0.f, 0.f);
    #pragma unroll
    for (int t = 0; t < 9; ++t) {
      if (offs[t] >= 0) {
        float4 v = *reinterpret_cast<const float4*>(r + offs[t]);
        acc.x += v.x; acc.y += v.y; acc.z += v.z; acc.w += v.w;
      }
    }
    acc.x *= (1.f / 9.f); acc.y *= (1.f / 9.f); acc.z *= (1.f / 9.f); acc.w *= (1.f / 9.f);
    *reinterpret_cast<float4*>(ob + ((size_t)i << 16)) = acc;
  }
}

// ---------------- launch ----------------
extern "C" void kernel_launch(void* const* d_in, const int* in_sizes, int n_in,
                              void* d_out, int out_size, void* d_ws, size_t ws_size,
                              hipStream_t stream) {
  const float* lq    = (const float*)d_in[0];
  const float* refdu = (const float*)d_in[1];
  const float* ref0  = (const float*)d_in[2];
  const float* ref1  = (const float*)d_in[3];
  const float* ref2  = (const float*)d_in[4];
  float* out = (float*)d_out;

  float* S      = (float*)d_ws;               // 16384
  float* qinv   = S + 16384;                  // 8192
  float* kinv   = qinv + 8192;                // 8192
  int*   maxidx = (int*)(kinv + 8192);        // 8192
  float* chunkv = (float*)(maxidx + 8192);    // 2*NCH*4096 = 2097152
  int*   chunki = (int*)(chunkv + 2097152);   // 2097152
  unsigned short* Ah = (unsigned short*)(chunki + 2097152);  // 2097152 ushorts
  unsigned short* Al = Ah + 2097152;
  unsigned short* Bh = Al + 2097152;
  unsigned short* Bl = Bh + 2097152;
  const size_t aux_bytes = (size_t)(40960 + 2097152 + 2097152) * 4 + (size_t)4 * 2097152 * 2;
  float* D = (float*)((char*)d_ws + ((aux_bytes + 255) & ~(size_t)255));

  const int ldD = 4352;                        // q' in [-128, 4224)
  const size_t Dsz = (size_t)4096 * ldD * 4;   // 71.3 MB
  const long long dstr = (long long)4096 * ldD;
  size_t avail = (ws_size > aux_bytes + 256) ? (ws_size - aux_bytes - 256) : 0;

  sumsq_k<<<dim3(16, 2, 2), 256, 0, stream>>>(lq, refdu, S);
  norm_k<<<dim3(64), 256, 0, stream>>>(S, qinv, kinv);

  if (avail >= 2 * Dsz) {
    // merged MFMA path: both batches' D resident
    conv_hl<<<dim3(2048), 256, 0, stream>>>(refdu, Ah, Al);
    conv_hl<<<dim3(2048), 256, 0, stream>>>(lq, Bh, Bl);
    gemm_mfma<<<dim3(64, 68, 2), 256, 0, stream>>>(Ah, Al, Bh, Bl, D, ldD, -128, dstr);
    reduce_max8<<<dim3(2, NCH, 2), 256, 0, stream>>>(D, ldD, -128, 0, kinv,
                                                     chunkv, chunki, 0, dstr);
  } else if (avail >= Dsz) {
    conv_hl<<<dim3(2048), 256, 0, stream>>>(refdu, Ah, Al);
    conv_hl<<<dim3(2048), 256, 0, stream>>>(lq, Bh, Bl);
    for (int n = 0; n < 2; ++n) {
      gemm_mfma<<<dim3(64, 68, 1), 256, 0, stream>>>(
          Ah + (size_t)n * 1048576, Al + (size_t)n * 1048576,
          Bh + (size_t)n * 1048576, Bl + (size_t)n * 1048576, D, ldD, -128, 0);
      reduce_max8<<<dim3(2, NCH, 1), 256, 0, stream>>>(D, ldD, -128, 0, kinv,
                                                       chunkv, chunki, n, 0);
    }
  } else {
    // stripe fallback: fp32 gemm, halved-width D
    const int Wq = 2048, ldS = Wq + 256;
    for (int n = 0; n < 2; ++n) {
      for (int Q0 = 0; Q0 < 4096; Q0 += Wq) {
        int C0 = Q0 - 128;
        gemm_d<<<dim3(32, ldS / 128, 1), 256, 0, stream>>>(
            refdu + (size_t)n * 1048576, lq + (size_t)n * 1048576, D, ldS, C0, 0);
        reduce_max8<<<dim3(Wq / 2048, NCH, 1), 256, 0, stream>>>(
            D, ldS, C0, Q0, kinv, chunkv, chunki, n, 0);
      }
    }
  }
  combine_k<<<dim3(32), 256, 0, stream>>>(chunkv, chunki, qinv, out, maxidx, NCH);

  tex0_lds<<<dim3(64, 2, 2),  256, 0, stream>>>(ref0, maxidx, out + 8192);
  tex1_lds<<<dim3(128, 2, 2), 256, 0, stream>>>(ref1, maxidx, out + 2105344);
  tex2_k<<<dim3(1024), 256, 0, stream>>>(ref2, maxidx, out + 6299648);
}

// Round 15
// 384.069 us; speedup vs baseline: 1.1311x; 1.0182x over previous
//
#include <hip/hip_runtime.h>
#include <math.h>

struct __attribute__((packed)) f4u { float v[4]; };  // 4B-aligned 4-float load

typedef __attribute__((ext_vector_type(8))) short bf16x8;   // 8 bf16 (4 VGPRs)
typedef __attribute__((ext_vector_type(4))) float f32x4;

#define KCH 16   // k per reduce chunk
#define NCH 256  // 4096 / KCH
#define LDF 40   // LDS fragment row stride (ushorts): 32 used + 8 pad (16B-aligned rows)

// ---------------- per-pixel channel sum-of-squares ----------------
__global__ __launch_bounds__(256) void sumsq_k(const float* __restrict__ lq,
                                               const float* __restrict__ refdu,
                                               float* __restrict__ S) {
  const float* src = blockIdx.z ? refdu : lq;
  const int n = blockIdx.y;
  const int h = blockIdx.x * 4 + (threadIdx.x >> 6);
  const int w = threadIdx.x & 63;
  const float* p = src + (size_t)n * 1048576 + h * 64 + w;
  float s0 = 0.f, s1 = 0.f, s2 = 0.f, s3 = 0.f;
  #pragma unroll 4
  for (int c = 0; c < 256; c += 4) {
    float x0 = p[(size_t)c * 4096];
    float x1 = p[(size_t)(c + 1) * 4096];
    float x2 = p[(size_t)(c + 2) * 4096];
    float x3 = p[(size_t)(c + 3) * 4096];
    s0 = fmaf(x0, x0, s0); s1 = fmaf(x1, x1, s1);
    s2 = fmaf(x2, x2, s2); s3 = fmaf(x3, x3, s3);
  }
  S[(blockIdx.z * 2 + n) * 4096 + h * 64 + w] = (s0 + s1) + (s2 + s3);
}

// ---------------- 3x3 box-sum -> inverse patch norms ----------------
__global__ __launch_bounds__(256) void norm_k(const float* __restrict__ S,
                                              float* __restrict__ qinv,
                                              float* __restrict__ kinv) {
  int idx = blockIdx.x * 256 + threadIdx.x;
  int pix = idx & 4095;
  int nn  = (idx >> 12) & 1;
  int arr = idx >> 13;
  int ph = pix >> 6, pw = pix & 63;
  const float* Sp = S + (arr * 2 + nn) * 4096;
  float sum = 0.f;
  #pragma unroll
  for (int dy = -1; dy <= 1; ++dy) {
    int hh = ph + dy;
    if ((unsigned)hh < 64u) {
      const float* r = Sp + hh * 64;
      #pragma unroll
      for (int dx = -1; dx <= 1; ++dx) {
        int ww = pw + dx;
        if ((unsigned)ww < 64u) sum += r[ww];
      }
    }
  }
  float inv = 1.0f / fmaxf(sqrtf(sum), 1e-12f);
  if (arr) kinv[nn * 4096 + pix] = inv;
  else     qinv[nn * 4096 + pix] = inv;
}

// ---------------- fp32 -> bf16 hi/lo split (RNE) + TRANSPOSE to [n][px][c] ----------------
// grid (64 px-tiles, 4 c-tiles, 2 n); block 256; LDS 64x64 tile transpose
__global__ __launch_bounds__(256) void conv_t(const float* __restrict__ src,
                                              unsigned short* __restrict__ hi,
                                              unsigned short* __restrict__ lo) {
  __shared__ unsigned short Lh[64][68], Ll[64][68];
  const int tid = threadIdx.x;
  const int px0 = blockIdx.x * 64;
  const int c0  = blockIdx.y * 64;
  const int n   = blockIdx.z;
  const float* s = src + ((size_t)n * 256 + c0) * 4096 + px0;
  #pragma unroll
  for (int i = 0; i < 4; ++i) {
    int c  = i * 16 + (tid >> 4);
    int p4 = (tid & 15) * 4;
    float4 v = *reinterpret_cast<const float4*>(s + (size_t)c * 4096 + p4);
    float xs[4] = {v.x, v.y, v.z, v.w};
    #pragma unroll
    for (int j = 0; j < 4; ++j) {
      float x = xs[j];
      unsigned u = __float_as_uint(x);
      unsigned hb = (u + 0x7FFFu + ((u >> 16) & 1u)) & 0xFFFF0000u;
      Lh[c][p4 + j] = (unsigned short)(hb >> 16);
      float r = x - __uint_as_float(hb);
      unsigned ur = __float_as_uint(r);
      Ll[c][p4 + j] = (unsigned short)((ur + 0x7FFFu + ((ur >> 16) & 1u)) >> 16);
    }
  }
  __syncthreads();
  const int px = tid >> 2;
  const int cq = (tid & 3) * 16;
  unsigned short hbuf[16], lbuf[16];
  #pragma unroll
  for (int j = 0; j < 16; ++j) { hbuf[j] = Lh[cq + j][px]; lbuf[j] = Ll[cq + j][px]; }
  size_t ob = ((size_t)n * 4096 + px0 + px) * 256 + c0 + cq;
  #pragma unroll
  for (int j = 0; j < 4; ++j) {
    *reinterpret_cast<ushort4*>(hi + ob + j * 4) =
        make_ushort4(hbuf[4 * j], hbuf[4 * j + 1], hbuf[4 * j + 2], hbuf[4 * j + 3]);
    *reinterpret_cast<ushort4*>(lo + ob + j * 4) =
        make_ushort4(lbuf[4 * j], lbuf[4 * j + 1], lbuf[4 * j + 2], lbuf[4 * j + 3]);
  }
}

// ---------------- MFMA GEMM: D[k][j'] = sum_c Ref[c][k]*LQ[c][C0+j'] ----------------
// Operands pre-transposed [n][px][c]: staging = linear b128 copy, no repack.
// grid (64, 68, nz); block 256 = 4 waves; tile 64k x 64j; wave owns 16 k-rows.
// bf16 hi/lo split: D = AhBh + AhBl + AlBh. sigma(lg,e) = ct + 8*lg + e for both operands.
__global__ __launch_bounds__(256) void gemm_mfma(const unsigned short* __restrict__ At_h,
                                                 const unsigned short* __restrict__ At_l,
                                                 const unsigned short* __restrict__ Bt_h,
                                                 const unsigned short* __restrict__ Bt_l,
                                                 float* __restrict__ Dbase,
                                                 int ldD, int C0, long long dstride) {
  __shared__ __align__(16) unsigned short LAh[64 * LDF], LAl[64 * LDF];
  __shared__ __align__(16) unsigned short LBh[64 * LDF], LBl[64 * LDF];
  const int tid = threadIdx.x;
  const int nz = blockIdx.z;
  const int k0 = blockIdx.x * 64;
  const int dcol0 = blockIdx.y * 64;
  const int jq0 = C0 + dcol0;
  float* D = Dbase + (size_t)nz * dstride;

  const bool oob = (jq0 < 0) || (jq0 + 64 > 4096);

  if (!oob) {
    const unsigned short* Ahb = At_h + (size_t)nz * 1048576;
    const unsigned short* Alb = At_l + (size_t)nz * 1048576;
    const unsigned short* Bhb = Bt_h + (size_t)nz * 1048576;
    const unsigned short* Blb = Bt_l + (size_t)nz * 1048576;

    // staging role: row r = tid>>2 (0..63), c-segment cs = (tid&3)*8
    const int r  = tid >> 2;
    const int cs = (tid & 3) * 8;
    const size_t gA = (size_t)(k0 + r) * 256 + cs;    // + ct per step
    const size_t gB = (size_t)(jq0 + r) * 256 + cs;
    const int sIdx = r * LDF + cs;

    // compute role
    const int wv = tid >> 6;
    const int lane = tid & 63;
    const int lm = lane & 15;
    const int lg = lane >> 4;
    const int offA = (wv * 16 + lm) * LDF + lg * 8;

    f32x4 acc[4];
    #pragma unroll
    for (int t = 0; t < 4; ++t) acc[t] = (f32x4){0.f, 0.f, 0.f, 0.f};

    for (int ct = 0; ct < 256; ct += 32) {
      __syncthreads();
      // ---- stage: 4 arrays x (1 b128 global load -> 1 b128 LDS write) ----
      {
        ulonglong2 vah = *reinterpret_cast<const ulonglong2*>(Ahb + gA + ct);
        ulonglong2 val = *reinterpret_cast<const ulonglong2*>(Alb + gA + ct);
        ulonglong2 vbh = *reinterpret_cast<const ulonglong2*>(Bhb + gB + ct);
        ulonglong2 vbl = *reinterpret_cast<const ulonglong2*>(Blb + gB + ct);
        *reinterpret_cast<ulonglong2*>(&LAh[sIdx]) = vah;
        *reinterpret_cast<ulonglong2*>(&LAl[sIdx]) = val;
        *reinterpret_cast<ulonglong2*>(&LBh[sIdx]) = vbh;
        *reinterpret_cast<ulonglong2*>(&LBl[sIdx]) = vbl;
      }
      __syncthreads();
      // ---- fragments (b128, conflict-free) + MFMA ----
      bf16x8 a_h = *reinterpret_cast<const bf16x8*>(&LAh[offA]);
      bf16x8 a_l = *reinterpret_cast<const bf16x8*>(&LAl[offA]);
      #pragma unroll
      for (int t = 0; t < 4; ++t) {
        const int offB = (t * 16 + lm) * LDF + lg * 8;
        bf16x8 b_h = *reinterpret_cast<const bf16x8*>(&LBh[offB]);
        bf16x8 b_l = *reinterpret_cast<const bf16x8*>(&LBl[offB]);
        acc[t] = __builtin_amdgcn_mfma_f32_16x16x32_bf16(a_h, b_h, acc[t], 0, 0, 0);
        acc[t] = __builtin_amdgcn_mfma_f32_16x16x32_bf16(a_h, b_l, acc[t], 0, 0, 0);
        acc[t] = __builtin_amdgcn_mfma_f32_16x16x32_bf16(a_l, b_h, acc[t], 0, 0, 0);
      }
    }
    // epilogue: row = k0 + wv*16 + lg*4 + r, col = dcol0 + t*16 + lm
    #pragma unroll
    for (int t = 0; t < 4; ++t) {
      #pragma unroll
      for (int rr = 0; rr < 4; ++rr) {
        D[(size_t)(k0 + wv * 16 + lg * 4 + rr) * ldD + dcol0 + t * 16 + lm] = acc[t][rr];
      }
    }
  } else {
    // zero-fill the 64x64 halo block
    const int row = tid & 63;
    const int csz = (tid >> 6) * 16;
    float* Dp = D + (size_t)(k0 + row) * ldD + dcol0 + csz;
    #pragma unroll
    for (int j = 0; j < 4; ++j)
      *reinterpret_cast<float4*>(Dp + j * 4) = make_float4(0.f, 0.f, 0.f, 0.f);
  }
}

// ---------------- fused 9-tap DIAGONAL reduce + max/argmax, 8 q per thread ----------------
__global__ __launch_bounds__(256) void reduce_max8(const float* __restrict__ Dbase,
                                                   int ldD, int C0, int Q0,
                                                   const float* __restrict__ kinv,
                                                   float* __restrict__ chunkv,
                                                   int* __restrict__ chunki,
                                                   int n0, long long dstride) {
  __shared__ float sk[KCH];
  const int n = n0 + blockIdx.z;
  const float* D = Dbase + (size_t)blockIdx.z * (size_t)dstride;
  const int k0 = blockIdx.y * KCH;
  const int kh = k0 >> 6;
  const int kwb = k0 & 63;
  if (threadIdx.x < KCH) sk[threadIdx.x] = kinv[n * 4096 + k0 + threadIdx.x];
  __syncthreads();
  const int q0 = Q0 + (blockIdx.x * 256 + threadIdx.x) * 8;
  const int qh = q0 >> 6;
  const int qw0 = q0 & 63;
  const bool up = (kh > 0) && (qh > 0);
  const bool dn = (kh < 63) && (qh < 63);
  const bool lf_ok = qw0 > 0;
  const bool rt_ok = qw0 < 56;
  float best[8]; int bidx[8];
  #pragma unroll
  for (int i = 0; i < 8; ++i) { best[i] = -INFINITY; bidx[i] = k0; }
  const float* Dq = D + (q0 - C0);
  const int step = ldD + 1;
  #pragma unroll 2
  for (int kk = 0; kk < KCH; ++kk) {
    const int kw = kwb + kk;
    const float* P = Dq + (size_t)(k0 + kk) * ldD;
    float r[8];
    {
      float4 c0 = *reinterpret_cast<const float4*>(P);
      float4 c1 = *reinterpret_cast<const float4*>(P + 4);
      r[0]=c0.x; r[1]=c0.y; r[2]=c0.z; r[3]=c0.w; r[4]=c1.x; r[5]=c1.y; r[6]=c1.z; r[7]=c1.w;
    }
    if (up) {
      float4 c0 = *reinterpret_cast<const float4*>(P - 64 * step);
      float4 c1 = *reinterpret_cast<const float4*>(P - 64 * step + 4);
      r[0]+=c0.x; r[1]+=c0.y; r[2]+=c0.z; r[3]+=c0.w; r[4]+=c1.x; r[5]+=c1.y; r[6]+=c1.z; r[7]+=c1.w;
    }
    if (dn) {
      float4 c0 = *reinterpret_cast<const float4*>(P + 64 * step);
      float4 c1 = *reinterpret_cast<const float4*>(P + 64 * step + 4);
      r[0]+=c0.x; r[1]+=c0.y; r[2]+=c0.z; r[3]+=c0.w; r[4]+=c1.x; r[5]+=c1.y; r[6]+=c1.z; r[7]+=c1.w;
    }
    if (kw > 0) {
      #pragma unroll
      for (int t = 0; t < 3; ++t) {
        if (t == 1 && !up) continue;
        if (t == 2 && !dn) continue;
        const int off = (t == 0) ? -step : (t == 1 ? -65 * step : 63 * step);
        f4u b0 = *reinterpret_cast<const f4u*>(P + off);
        f4u b1 = *reinterpret_cast<const f4u*>(P + off + 4);
        r[0] += lf_ok ? b0.v[0] : 0.f; r[1]+=b0.v[1]; r[2]+=b0.v[2]; r[3]+=b0.v[3];
        r[4]+=b1.v[0]; r[5]+=b1.v[1]; r[6]+=b1.v[2]; r[7]+=b1.v[3];
      }
    }
    if (kw < 63) {
      #pragma unroll
      for (int t = 0; t < 3; ++t) {
        if (t == 1 && !up) continue;
        if (t == 2 && !dn) continue;
        const int off = (t == 0) ? step : (t == 1 ? -63 * step : 65 * step);
        f4u b0 = *reinterpret_cast<const f4u*>(P + off);
        f4u b1 = *reinterpret_cast<const f4u*>(P + off + 4);
        r[0]+=b0.v[0]; r[1]+=b0.v[1]; r[2]+=b0.v[2]; r[3]+=b0.v[3];
        r[4]+=b1.v[0]; r[5]+=b1.v[1]; r[6]+=b1.v[2]; r[7] += rt_ok ? b1.v[3] : 0.f;
      }
    }
    const float s = sk[kk];
    const int k = k0 + kk;
    #pragma unroll
    for (int i = 0; i < 8; ++i) {
      float v = r[i] * s;
      if (v > best[i]) { best[i] = v; bidx[i] = k; }
    }
  }
  const int ob = (n * NCH + blockIdx.y) * 4096 + q0;
  *reinterpret_cast<float4*>(chunkv + ob)     = make_float4(best[0], best[1], best[2], best[3]);
  *reinterpret_cast<float4*>(chunkv + ob + 4) = make_float4(best[4], best[5], best[6], best[7]);
  *reinterpret_cast<int4*>(chunki + ob)     = make_int4(bidx[0], bidx[1], bidx[2], bidx[3]);
  *reinterpret_cast<int4*>(chunki + ob + 4) = make_int4(bidx[4], bidx[5], bidx[6], bidx[7]);
}

// ---------------- combine chunks ----------------
__global__ __launch_bounds__(256) void combine_k(const float* __restrict__ chunkv,
                                                 const int* __restrict__ chunki,
                                                 const float* __restrict__ qinv,
                                                 float* __restrict__ out_sa,
                                                 int* __restrict__ maxidx, int nch) {
  int t = blockIdx.x * 256 + threadIdx.x;
  int n = t >> 12, q = t & 4095;
  float best = -INFINITY;
  int bi = 0;
  for (int ch = 0; ch < nch; ++ch) {
    int ii = (n * nch + ch) * 4096 + q;
    float v = chunkv[ii];
    int ix = chunki[ii];
    if (v > best) { best = v; bi = ix; }
  }
  maxidx[t] = bi;
  out_sa[t] = best * qinv[t];
}

// ---------------- fp32 GEMM (stripe fallback only) ----------------
__global__ __launch_bounds__(256) void gemm_d(const float* __restrict__ Abase,
                                              const float* __restrict__ Bbase,
                                              float* __restrict__ Dbase,
                                              int ldD, int C0, long long dstride) {
  __shared__ __align__(16) float As[2][8][128];
  __shared__ __align__(16) float Bs[2][8][128];
  const int tid = threadIdx.x;
  const int nz = blockIdx.z;
  const int k0 = blockIdx.x * 128;
  const int j0 = blockIdx.y * 128;
  const float* A = Abase + (size_t)nz * 1048576;
  const float* B = Bbase + (size_t)nz * 1048576;
  float* D = Dbase + (size_t)nz * dstride;
  const int ty = tid >> 4, tx = tid & 15, lr = tid >> 5, lc = (tid & 31) << 2;
  float acc[8][8];
  #pragma unroll
  for (int i = 0; i < 8; ++i)
    #pragma unroll
    for (int j = 0; j < 8; ++j) acc[i][j] = 0.f;
  const bool oob = (C0 + j0 < 0) || (C0 + j0 + 128 > 4096);
  if (!oob) {
    const float* Ap = A + k0 + lc;
    const float* Bp = B + (C0 + j0) + lc;
    float4 av = *reinterpret_cast<const float4*>(Ap + (size_t)lr * 4096);
    float4 bv = *reinterpret_cast<const float4*>(Bp + (size_t)lr * 4096);
    *reinterpret_cast<float4*>(&As[0][lr][lc]) = av;
    *reinterpret_cast<float4*>(&Bs[0][lr][lc]) = bv;
    for (int ct = 0; ct < 256; ct += 8) {
      const int buf = (ct >> 3) & 1;
      __syncthreads();
      if (ct + 8 < 256) {
        av = *reinterpret_cast<const float4*>(Ap + (size_t)(ct + 8 + lr) * 4096);
        bv = *reinterpret_cast<const float4*>(Bp + (size_t)(ct + 8 + lr) * 4096);
      }
      #pragma unroll
      for (int kc = 0; kc < 8; ++kc) {
        float a[8], b[8];
        *reinterpret_cast<float4*>(&a[0]) = *reinterpret_cast<const float4*>(&As[buf][kc][ty * 4]);
        *reinterpret_cast<float4*>(&a[4]) = *reinterpret_cast<const float4*>(&As[buf][kc][64 + ty * 4]);
        *reinterpret_cast<float4*>(&b[0]) = *reinterpret_cast<const float4*>(&Bs[buf][kc][tx * 4]);
        *reinterpret_cast<float4*>(&b[4]) = *reinterpret_cast<const float4*>(&Bs[buf][kc][64 + tx * 4]);
        #pragma unroll
        for (int i = 0; i < 8; ++i)
          #pragma unroll
          for (int j = 0; j < 8; ++j)
            acc[i][j] = fmaf(a[i], b[j], acc[i][j]);
      }
      if (ct + 8 < 256) {
        *reinterpret_cast<float4*>(&As[buf ^ 1][lr][lc]) = av;
        *reinterpret_cast<float4*>(&Bs[buf ^ 1][lr][lc]) = bv;
      }
    }
  }
  #pragma unroll
  for (int half = 0; half < 2; ++half)
    #pragma unroll
    for (int i = 0; i < 4; ++i) {
      float* Dp = D + (size_t)(k0 + half * 64 + ty * 4 + i) * ldD + j0;
      *reinterpret_cast<float4*>(Dp + tx * 4)      = *reinterpret_cast<const float4*>(&acc[half * 4 + i][0]);
      *reinterpret_cast<float4*>(Dp + 64 + tx * 4) = *reinterpret_cast<const float4*>(&acc[half * 4 + i][4]);
    }
}

// ---------------- tex0: LDS-staged gather, 4 channels interleaved ----------------
__global__ __launch_bounds__(256) void tex0_lds(const float* __restrict__ ref,
                                                const int* __restrict__ maxidx,
                                                float* __restrict__ outp) {
  __shared__ __align__(16) float4 L[4096];
  const int cq = blockIdx.x;
  const int n  = blockIdx.y;
  const int half = blockIdx.z;
  const int tid = threadIdx.x;
  const float* p0 = ref + (((size_t)n * 256 + cq * 4) << 12);
  for (int i = 0; i < 16; ++i) {
    int px = i * 256 + tid;
    L[px] = make_float4(p0[px], p0[px + 4096], p0[px + 8192], p0[px + 12288]);
  }
  __syncthreads();
  const int* mi = maxidx + n * 4096;
  float* ob = outp + (((size_t)n * 256 + cq * 4) << 12);
  for (int i = 0; i < 8; ++i) {
    int px = half * 2048 + i * 256 + tid;
    int y = px >> 6, x = px & 63;
    float ax = 0.f, ay = 0.f, az = 0.f, aw = 0.f;
    #pragma unroll
    for (int a = -1; a <= 1; ++a) {
      int jh = y + a;
      if ((unsigned)jh < 64u) {
        #pragma unroll
        for (int b = -1; b <= 1; ++b) {
          int jw = x + b;
          if ((unsigned)jw < 64u) {
            int m = mi[jh * 64 + jw];
            int rh = (m >> 6) - a;
            int cx = (m & 63) - b;
            if ((unsigned)rh < 64u && (unsigned)cx < 64u) {
              float4 v = L[rh * 64 + cx];
              ax += v.x; ay += v.y; az += v.z; aw += v.w;
            }
          }
        }
      }
    }
    ob[px]         = ax * (1.f / 9.f);
    ob[px + 4096]  = ay * (1.f / 9.f);
    ob[px + 8192]  = az * (1.f / 9.f);
    ob[px + 12288] = aw * (1.f / 9.f);
  }
}

// ---------------- tex1: LDS-staged gather, one 128x128 plane ----------------
__global__ __launch_bounds__(256) void tex1_lds(const float* __restrict__ ref,
                                                const int* __restrict__ maxidx,
                                                float* __restrict__ outp) {
  __shared__ __align__(16) float Lf[16384];
  const int c = blockIdx.x;
  const int n = blockIdx.y;
  const int half = blockIdx.z;
  const int tid = threadIdx.x;
  const float* p0 = ref + (((size_t)n * 128 + c) << 14);
  float4* L4 = (float4*)Lf;
  const float4* g4 = (const float4*)p0;
  for (int i = 0; i < 16; ++i) {
    int g = i * 256 + tid;
    L4[g] = g4[g];
  }
  __syncthreads();
  const int* mi = maxidx + n * 4096;
  float* ob = outp + (((size_t)n * 128 + c) << 14);
  for (int i = 0; i < 16; ++i) {
    int pp = half * 4096 + i * 256 + tid;
    int xp = pp & 63;
    int y  = pp >> 6;
    int jh0 = y >> 1;
    float a0 = 0.f, a1 = 0.f;
    #pragma unroll
    for (int a = -1; a <= 1; ++a) {
      int jh = jh0 + a;
      if ((unsigned)jh < 64u) {
        #pragma unroll
        for (int b = -1; b <= 1; ++b) {
          int jw = xp + b;
          if ((unsigned)jw < 64u) {
            int m = mi[jh * 64 + jw];
            int rh = (m >> 6) - a;
            int cx = (m & 63) - b;
            if ((unsigned)rh < 64u && (unsigned)cx < 64u) {
              int off = ((rh << 1) + (y & 1)) * 128 + (cx << 1);
              float2 v = *reinterpret_cast<const float2*>(&Lf[off]);
              a0 += v.x; a1 += v.y;
            }
          }
        }
      }
    }
    *reinterpret_cast<float2*>(&ob[y * 128 + xp * 2]) =
        make_float2(a0 * (1.f / 9.f), a1 * (1.f / 9.f));
  }
}

// ---------------- tex2: global float4 taps ----------------
__global__ __launch_bounds__(256) void tex2_k(const float* __restrict__ ref,
                                              const int* __restrict__ maxidx,
                                              float* __restrict__ outp) {
  int gid = blockIdx.x * 256 + threadIdx.x;
  const int xg = gid & 63;
  const int y  = (gid >> 6) & 255;
  const int cc = (gid >> 14) & 7;
  const int n  = gid >> 17;
  const int jh0 = y >> 2;
  const int* mi = maxidx + n * 4096;
  int offs[9];
  #pragma unroll
  for (int a = -1; a <= 1; ++a) {
    #pragma unroll
    for (int b = -1; b <= 1; ++b) {
      const int t = (a + 1) * 3 + (b + 1);
      int jh = jh0 + a, jw = xg + b;
      int off = -1;
      if ((unsigned)jh < 64u && (unsigned)jw < 64u) {
        int m = mi[jh * 64 + jw];
        int rh = (m >> 6) - jh + jh0;
        int cx = (m & 63) - jw + xg;
        if ((unsigned)rh < 64u && (unsigned)cx < 64u)
          off = ((rh << 2) + (y & 3)) * 256 + (cx << 2);
      }
      offs[t] = off;
    }
  }
  const float* rb = ref + (((size_t)n * 64 + cc * 8) << 16);
  float* ob = outp + ((((size_t)n * 64 + cc * 8) * 256 + y) << 8) + xg * 4;
  #pragma unroll
  for (int i = 0; i < 8; ++i) {
    const float* r = rb + ((size_t)i << 16);
    float4 acc = make_float4(0.f, 0.f, 0.f, 0.f);
    #pragma unroll
    for (int t = 0; t < 9; ++t) {
      if (offs[t] >= 0) {
        float4 v = *reinterpret_cast<const float4*>(r + offs[t]);
        acc.x += v.x; acc.y += v.y; acc.z += v.z; acc.w += v.w;
      }
    }
    acc.x *= (1.f / 9.f); acc.y *= (1.f / 9.f); acc.z *= (1.f / 9.f); acc.w *= (1.f / 9.f);
    *reinterpret_cast<float4*>(ob + ((size_t)i << 16)) = acc;
  }
}

// ---------------- launch ----------------
extern "C" void kernel_launch(void* const* d_in, const int* in_sizes, int n_in,
                              void* d_out, int out_size, void* d_ws, size_t ws_size,
                              hipStream_t stream) {
  const float* lq    = (const float*)d_in[0];
  const float* refdu = (const float*)d_in[1];
  const float* ref0  = (const float*)d_in[2];
  const float* ref1  = (const float*)d_in[3];
  const float* ref2  = (const float*)d_in[4];
  float* out = (float*)d_out;

  float* S      = (float*)d_ws;               // 16384
  float* qinv   = S + 16384;                  // 8192
  float* kinv   = qinv + 8192;                // 8192
  int*   maxidx = (int*)(kinv + 8192);        // 8192
  float* chunkv = (float*)(maxidx + 8192);    // 2*NCH*4096 = 2097152
  int*   chunki = (int*)(chunkv + 2097152);   // 2097152
  unsigned short* Ah = (unsigned short*)(chunki + 2097152);  // 2097152 ushorts each
  unsigned short* Al = Ah + 2097152;
  unsigned short* Bh = Al + 2097152;
  unsigned short* Bl = Bh + 2097152;
  const size_t aux_bytes = (size_t)(40960 + 2097152 + 2097152) * 4 + (size_t)4 * 2097152 * 2;
  float* D = (float*)((char*)d_ws + ((aux_bytes + 255) & ~(size_t)255));

  const int ldD = 4352;                        // q' in [-128, 4224)
  const size_t Dsz = (size_t)4096 * ldD * 4;   // 71.3 MB
  const long long dstr = (long long)4096 * ldD;
  size_t avail = (ws_size > aux_bytes + 256) ? (ws_size - aux_bytes - 256) : 0;

  sumsq_k<<<dim3(16, 2, 2), 256, 0, stream>>>(lq, refdu, S);
  norm_k<<<dim3(64), 256, 0, stream>>>(S, qinv, kinv);

  if (avail >= 2 * Dsz) {
    // merged MFMA path: both batches' D resident
    conv_t<<<dim3(64, 4, 2), 256, 0, stream>>>(refdu, Ah, Al);
    conv_t<<<dim3(64, 4, 2), 256, 0, stream>>>(lq, Bh, Bl);
    gemm_mfma<<<dim3(64, 68, 2), 256, 0, stream>>>(Ah, Al, Bh, Bl, D, ldD, -128, dstr);
    reduce_max8<<<dim3(2, NCH, 2), 256, 0, stream>>>(D, ldD, -128, 0, kinv,
                                                     chunkv, chunki, 0, dstr);
  } else if (avail >= Dsz) {
    conv_t<<<dim3(64, 4, 2), 256, 0, stream>>>(refdu, Ah, Al);
    conv_t<<<dim3(64, 4, 2), 256, 0, stream>>>(lq, Bh, Bl);
    for (int n = 0; n < 2; ++n) {
      gemm_mfma<<<dim3(64, 68, 1), 256, 0, stream>>>(
          Ah + (size_t)n * 1048576, Al + (size_t)n * 1048576,
          Bh + (size_t)n * 1048576, Bl + (size_t)n * 1048576, D, ldD, -128, 0);
      reduce_max8<<<dim3(2, NCH, 1), 256, 0, stream>>>(D, ldD, -128, 0, kinv,
                                                       chunkv, chunki, n, 0);
    }
  } else {
    // stripe fallback: fp32 gemm, halved-width D
    const int Wq = 2048, ldS = Wq + 256;
    for (int n = 0; n < 2; ++n) {
      for (int Q0 = 0; Q0 < 4096; Q0 += Wq) {
        int C0 = Q0 - 128;
        gemm_d<<<dim3(32, ldS / 128, 1), 256, 0, stream>>>(
            refdu + (size_t)n * 1048576, lq + (size_t)n * 1048576, D, ldS, C0, 0);
        reduce_max8<<<dim3(Wq / 2048, NCH, 1), 256, 0, stream>>>(
            D, ldS, C0, Q0, kinv, chunkv, chunki, n, 0);
      }
    }
  }
  combine_k<<<dim3(32), 256, 0, stream>>>(chunkv, chunki, qinv, out, maxidx, NCH);

  tex0_lds<<<dim3(64, 2, 2),  256, 0, stream>>>(ref0, maxidx, out + 8192);
  tex1_lds<<<dim3(128, 2, 2), 256, 0, stream>>>(ref1, maxidx, out + 2105344);
  tex2_k<<<dim3(1024), 256, 0, stream>>>(ref2, maxidx, out + 6299648);
}

// Round 16
// 383.338 us; speedup vs baseline: 1.1332x; 1.0019x over previous
//
#include <hip/hip_runtime.h>
#include <math.h>

struct __attribute__((packed)) f4u { float v[4]; };  // 4B-aligned 4-float load

typedef __attribute__((ext_vector_type(8))) short bf16x8;   // 8 bf16 (4 VGPRs)
typedef __attribute__((ext_vector_type(4))) float f32x4;

#define KCH 16   // k per reduce chunk
#define NCH 256  // 4096 / KCH
#define LDF 40   // LDS fragment row stride (ushorts): 32 used + 8 pad (16B-aligned rows)

// ---------------- per-pixel channel sum-of-squares ----------------
__global__ __launch_bounds__(256) void sumsq_k(const float* __restrict__ lq,
                                               const float* __restrict__ refdu,
                                               float* __restrict__ S) {
  const float* src = blockIdx.z ? refdu : lq;
  const int n = blockIdx.y;
  const int h = blockIdx.x * 4 + (threadIdx.x >> 6);
  const int w = threadIdx.x & 63;
  const float* p = src + (size_t)n * 1048576 + h * 64 + w;
  float s0 = 0.f, s1 = 0.f, s2 = 0.f, s3 = 0.f;
  #pragma unroll 4
  for (int c = 0; c < 256; c += 4) {
    float x0 = p[(size_t)c * 4096];
    float x1 = p[(size_t)(c + 1) * 4096];
    float x2 = p[(size_t)(c + 2) * 4096];
    float x3 = p[(size_t)(c + 3) * 4096];
    s0 = fmaf(x0, x0, s0); s1 = fmaf(x1, x1, s1);
    s2 = fmaf(x2, x2, s2); s3 = fmaf(x3, x3, s3);
  }
  S[(blockIdx.z * 2 + n) * 4096 + h * 64 + w] = (s0 + s1) + (s2 + s3);
}

// ---------------- 3x3 box-sum -> inverse patch norms ----------------
__global__ __launch_bounds__(256) void norm_k(const float* __restrict__ S,
                                              float* __restrict__ qinv,
                                              float* __restrict__ kinv) {
  int idx = blockIdx.x * 256 + threadIdx.x;
  int pix = idx & 4095;
  int nn  = (idx >> 12) & 1;
  int arr = idx >> 13;
  int ph = pix >> 6, pw = pix & 63;
  const float* Sp = S + (arr * 2 + nn) * 4096;
  float sum = 0.f;
  #pragma unroll
  for (int dy = -1; dy <= 1; ++dy) {
    int hh = ph + dy;
    if ((unsigned)hh < 64u) {
      const float* r = Sp + hh * 64;
      #pragma unroll
      for (int dx = -1; dx <= 1; ++dx) {
        int ww = pw + dx;
        if ((unsigned)ww < 64u) sum += r[ww];
      }
    }
  }
  float inv = 1.0f / fmaxf(sqrtf(sum), 1e-12f);
  if (arr) kinv[nn * 4096 + pix] = inv;
  else     qinv[nn * 4096 + pix] = inv;
}

// ---------------- fp32 -> bf16 hi/lo split (RNE) + TRANSPOSE to [n][px][c] ----------------
// grid (64 px-tiles, 4 c-tiles, 2 n); block 256; LDS 64x64 tile transpose
__global__ __launch_bounds__(256) void conv_t(const float* __restrict__ src,
                                              unsigned short* __restrict__ hi,
                                              unsigned short* __restrict__ lo) {
  __shared__ unsigned short Lh[64][68], Ll[64][68];
  const int tid = threadIdx.x;
  const int px0 = blockIdx.x * 64;
  const int c0  = blockIdx.y * 64;
  const int n   = blockIdx.z;
  const float* s = src + ((size_t)n * 256 + c0) * 4096 + px0;
  #pragma unroll
  for (int i = 0; i < 4; ++i) {
    int c  = i * 16 + (tid >> 4);
    int p4 = (tid & 15) * 4;
    float4 v = *reinterpret_cast<const float4*>(s + (size_t)c * 4096 + p4);
    float xs[4] = {v.x, v.y, v.z, v.w};
    #pragma unroll
    for (int j = 0; j < 4; ++j) {
      float x = xs[j];
      unsigned u = __float_as_uint(x);
      unsigned hb = (u + 0x7FFFu + ((u >> 16) & 1u)) & 0xFFFF0000u;
      Lh[c][p4 + j] = (unsigned short)(hb >> 16);
      float r = x - __uint_as_float(hb);
      unsigned ur = __float_as_uint(r);
      Ll[c][p4 + j] = (unsigned short)((ur + 0x7FFFu + ((ur >> 16) & 1u)) >> 16);
    }
  }
  __syncthreads();
  const int px = tid >> 2;
  const int cq = (tid & 3) * 16;
  unsigned short hbuf[16], lbuf[16];
  #pragma unroll
  for (int j = 0; j < 16; ++j) { hbuf[j] = Lh[cq + j][px]; lbuf[j] = Ll[cq + j][px]; }
  size_t ob = ((size_t)n * 4096 + px0 + px) * 256 + c0 + cq;
  #pragma unroll
  for (int j = 0; j < 4; ++j) {
    *reinterpret_cast<ushort4*>(hi + ob + j * 4) =
        make_ushort4(hbuf[4 * j], hbuf[4 * j + 1], hbuf[4 * j + 2], hbuf[4 * j + 3]);
    *reinterpret_cast<ushort4*>(lo + ob + j * 4) =
        make_ushort4(lbuf[4 * j], lbuf[4 * j + 1], lbuf[4 * j + 2], lbuf[4 * j + 3]);
  }
}

// ---------------- MFMA GEMM: D[k][j'] = sum_c Ref[c][k]*LQ[c][C0+j'] ----------------
// Operands pre-transposed [n][px][c]: staging = linear b128 copy, no repack.
// grid (64, 68, nz); block 256 = 4 waves; tile 64k x 64j; wave owns 16 k-rows.
// bf16 hi/lo split: D = AhBh + AhBl + AlBh. sigma(lg,e) = ct + 8*lg + e for both operands.
__global__ __launch_bounds__(256) void gemm_mfma(const unsigned short* __restrict__ At_h,
                                                 const unsigned short* __restrict__ At_l,
                                                 const unsigned short* __restrict__ Bt_h,
                                                 const unsigned short* __restrict__ Bt_l,
                                                 float* __restrict__ Dbase,
                                                 int ldD, int C0, long long dstride) {
  __shared__ __align__(16) unsigned short LAh[64 * LDF], LAl[64 * LDF];
  __shared__ __align__(16) unsigned short LBh[64 * LDF], LBl[64 * LDF];
  const int tid = threadIdx.x;
  const int nz = blockIdx.z;
  const int k0 = blockIdx.x * 64;
  const int dcol0 = blockIdx.y * 64;
  const int jq0 = C0 + dcol0;
  float* D = Dbase + (size_t)nz * dstride;

  const bool oob = (jq0 < 0) || (jq0 + 64 > 4096);

  if (!oob) {
    const unsigned short* Ahb = At_h + (size_t)nz * 1048576;
    const unsigned short* Alb = At_l + (size_t)nz * 1048576;
    const unsigned short* Bhb = Bt_h + (size_t)nz * 1048576;
    const unsigned short* Blb = Bt_l + (size_t)nz * 1048576;

    // staging role: row r = tid>>2 (0..63), c-segment cs = (tid&3)*8
    const int r  = tid >> 2;
    const int cs = (tid & 3) * 8;
    const size_t gA = (size_t)(k0 + r) * 256 + cs;    // + ct per step
    const size_t gB = (size_t)(jq0 + r) * 256 + cs;
    const int sIdx = r * LDF + cs;

    // compute role
    const int wv = tid >> 6;
    const int lane = tid & 63;
    const int lm = lane & 15;
    const int lg = lane >> 4;
    const int offA = (wv * 16 + lm) * LDF + lg * 8;

    f32x4 acc[4];
    #pragma unroll
    for (int t = 0; t < 4; ++t) acc[t] = (f32x4){0.f, 0.f, 0.f, 0.f};

    for (int ct = 0; ct < 256; ct += 32) {
      __syncthreads();
      // ---- stage: 4 arrays x (1 b128 global load -> 1 b128 LDS write) ----
      {
        ulonglong2 vah = *reinterpret_cast<const ulonglong2*>(Ahb + gA + ct);
        ulonglong2 val = *reinterpret_cast<const ulonglong2*>(Alb + gA + ct);
        ulonglong2 vbh = *reinterpret_cast<const ulonglong2*>(Bhb + gB + ct);
        ulonglong2 vbl = *reinterpret_cast<const ulonglong2*>(Blb + gB + ct);
        *reinterpret_cast<ulonglong2*>(&LAh[sIdx]) = vah;
        *reinterpret_cast<ulonglong2*>(&LAl[sIdx]) = val;
        *reinterpret_cast<ulonglong2*>(&LBh[sIdx]) = vbh;
        *reinterpret_cast<ulonglong2*>(&LBl[sIdx]) = vbl;
      }
      __syncthreads();
      // ---- fragments (b128, conflict-free) + MFMA ----
      bf16x8 a_h = *reinterpret_cast<const bf16x8*>(&LAh[offA]);
      bf16x8 a_l = *reinterpret_cast<const bf16x8*>(&LAl[offA]);
      #pragma unroll
      for (int t = 0; t < 4; ++t) {
        const int offB = (t * 16 + lm) * LDF + lg * 8;
        bf16x8 b_h = *reinterpret_cast<const bf16x8*>(&LBh[offB]);
        bf16x8 b_l = *reinterpret_cast<const bf16x8*>(&LBl[offB]);
        acc[t] = __builtin_amdgcn_mfma_f32_16x16x32_bf16(a_h, b_h, acc[t], 0, 0, 0);
        acc[t] = __builtin_amdgcn_mfma_f32_16x16x32_bf16(a_h, b_l, acc[t], 0, 0, 0);
        acc[t] = __builtin_amdgcn_mfma_f32_16x16x32_bf16(a_l, b_h, acc[t], 0, 0, 0);
      }
    }
    // epilogue: row = k0 + wv*16 + lg*4 + r, col = dcol0 + t*16 + lm
    #pragma unroll
    for (int t = 0; t < 4; ++t) {
      #pragma unroll
      for (int rr = 0; rr < 4; ++rr) {
        D[(size_t)(k0 + wv * 16 + lg * 4 + rr) * ldD + dcol0 + t * 16 + lm] = acc[t][rr];
      }
    }
  } else {
    // zero-fill the 64x64 halo block
    const int row = tid & 63;
    const int csz = (tid >> 6) * 16;
    float* Dp = D + (size_t)(k0 + row) * ldD + dcol0 + csz;
    #pragma unroll
    for (int j = 0; j < 4; ++j)
      *reinterpret_cast<float4*>(Dp + j * 4) = make_float4(0.f, 0.f, 0.f, 0.f);
  }
}

// ---------------- fused 9-tap DIAGONAL reduce + max/argmax, 8 q per thread ----------------
__global__ __launch_bounds__(256) void reduce_max8(const float* __restrict__ Dbase,
                                                   int ldD, int C0, int Q0,
                                                   const float* __restrict__ kinv,
                                                   float* __restrict__ chunkv,
                                                   int* __restrict__ chunki,
                                                   int n0, long long dstride) {
  __shared__ float sk[KCH];
  const int n = n0 + blockIdx.z;
  const float* D = Dbase + (size_t)blockIdx.z * (size_t)dstride;
  const int k0 = blockIdx.y * KCH;
  const int kh = k0 >> 6;
  const int kwb = k0 & 63;
  if (threadIdx.x < KCH) sk[threadIdx.x] = kinv[n * 4096 + k0 + threadIdx.x];
  __syncthreads();
  const int q0 = Q0 + (blockIdx.x * 256 + threadIdx.x) * 8;
  const int qh = q0 >> 6;
  const int qw0 = q0 & 63;
  const bool up = (kh > 0) && (qh > 0);
  const bool dn = (kh < 63) && (qh < 63);
  const bool lf_ok = qw0 > 0;
  const bool rt_ok = qw0 < 56;
  float best[8]; int bidx[8];
  #pragma unroll
  for (int i = 0; i < 8; ++i) { best[i] = -INFINITY; bidx[i] = k0; }
  const float* Dq = D + (q0 - C0);
  const int step = ldD + 1;
  #pragma unroll 2
  for (int kk = 0; kk < KCH; ++kk) {
    const int kw = kwb + kk;
    const float* P = Dq + (size_t)(k0 + kk) * ldD;
    float r[8];
    {
      float4 c0 = *reinterpret_cast<const float4*>(P);
      float4 c1 = *reinterpret_cast<const float4*>(P + 4);
      r[0]=c0.x; r[1]=c0.y; r[2]=c0.z; r[3]=c0.w; r[4]=c1.x; r[5]=c1.y; r[6]=c1.z; r[7]=c1.w;
    }
    if (up) {
      float4 c0 = *reinterpret_cast<const float4*>(P - 64 * step);
      float4 c1 = *reinterpret_cast<const float4*>(P - 64 * step + 4);
      r[0]+=c0.x; r[1]+=c0.y; r[2]+=c0.z; r[3]+=c0.w; r[4]+=c1.x; r[5]+=c1.y; r[6]+=c1.z; r[7]+=c1.w;
    }
    if (dn) {
      float4 c0 = *reinterpret_cast<const float4*>(P + 64 * step);
      float4 c1 = *reinterpret_cast<const float4*>(P + 64 * step + 4);
      r[0]+=c0.x; r[1]+=c0.y; r[2]+=c0.z; r[3]+=c0.w; r[4]+=c1.x; r[5]+=c1.y; r[6]+=c1.z; r[7]+=c1.w;
    }
    if (kw > 0) {
      #pragma unroll
      for (int t = 0; t < 3; ++t) {
        if (t == 1 && !up) continue;
        if (t == 2 && !dn) continue;
        const int off = (t == 0) ? -step : (t == 1 ? -65 * step : 63 * step);
        f4u b0 = *reinterpret_cast<const f4u*>(P + off);
        f4u b1 = *reinterpret_cast<const f4u*>(P + off + 4);
        r[0] += lf_ok ? b0.v[0] : 0.f; r[1]+=b0.v[1]; r[2]+=b0.v[2]; r[3]+=b0.v[3];
        r[4]+=b1.v[0]; r[5]+=b1.v[1]; r[6]+=b1.v[2]; r[7]+=b1.v[3];
      }
    }
    if (kw < 63) {
      #pragma unroll
      for (int t = 0; t < 3; ++t) {
        if (t == 1 && !up) continue;
        if (t == 2 && !dn) continue;
        const int off = (t == 0) ? step : (t == 1 ? -63 * step : 65 * step);
        f4u b0 = *reinterpret_cast<const f4u*>(P + off);
        f4u b1 = *reinterpret_cast<const f4u*>(P + off + 4);
        r[0]+=b0.v[0]; r[1]+=b0.v[1]; r[2]+=b0.v[2]; r[3]+=b0.v[3];
        r[4]+=b1.v[0]; r[5]+=b1.v[1]; r[6]+=b1.v[2]; r[7] += rt_ok ? b1.v[3] : 0.f;
      }
    }
    const float s = sk[kk];
    const int k = k0 + kk;
    #pragma unroll
    for (int i = 0; i < 8; ++i) {
      float v = r[i] * s;
      if (v > best[i]) { best[i] = v; bidx[i] = k; }
    }
  }
  const int ob = (n * NCH + blockIdx.y) * 4096 + q0;
  *reinterpret_cast<float4*>(chunkv + ob)     = make_float4(best[0], best[1], best[2], best[3]);
  *reinterpret_cast<float4*>(chunkv + ob + 4) = make_float4(best[4], best[5], best[6], best[7]);
  *reinterpret_cast<int4*>(chunki + ob)     = make_int4(bidx[0], bidx[1], bidx[2], bidx[3]);
  *reinterpret_cast<int4*>(chunki + ob + 4) = make_int4(bidx[4], bidx[5], bidx[6], bidx[7]);
}

// ---------------- combine chunks ----------------
__global__ __launch_bounds__(256) void combine_k(const float* __restrict__ chunkv,
                                                 const int* __restrict__ chunki,
                                                 const float* __restrict__ qinv,
                                                 float* __restrict__ out_sa,
                                                 int* __restrict__ maxidx, int nch) {
  int t = blockIdx.x * 256 + threadIdx.x;
  int n = t >> 12, q = t & 4095;
  float best = -INFINITY;
  int bi = 0;
  for (int ch = 0; ch < nch; ++ch) {
    int ii = (n * nch + ch) * 4096 + q;
    float v = chunkv[ii];
    int ix = chunki[ii];
    if (v > best) { best = v; bi = ix; }
  }
  maxidx[t] = bi;
  out_sa[t] = best * qinv[t];
}

// ---------------- fp32 GEMM (stripe fallback only) ----------------
__global__ __launch_bounds__(256) void gemm_d(const float* __restrict__ Abase,
                                              const float* __restrict__ Bbase,
                                              float* __restrict__ Dbase,
                                              int ldD, int C0, long long dstride) {
  __shared__ __align__(16) float As[2][8][128];
  __shared__ __align__(16) float Bs[2][8][128];
  const int tid = threadIdx.x;
  const int nz = blockIdx.z;
  const int k0 = blockIdx.x * 128;
  const int j0 = blockIdx.y * 128;
  const float* A = Abase + (size_t)nz * 1048576;
  const float* B = Bbase + (size_t)nz * 1048576;
  float* D = Dbase + (size_t)nz * dstride;
  const int ty = tid >> 4, tx = tid & 15, lr = tid >> 5, lc = (tid & 31) << 2;
  float acc[8][8];
  #pragma unroll
  for (int i = 0; i < 8; ++i)
    #pragma unroll
    for (int j = 0; j < 8; ++j) acc[i][j] = 0.f;
  const bool oob = (C0 + j0 < 0) || (C0 + j0 + 128 > 4096);
  if (!oob) {
    const float* Ap = A + k0 + lc;
    const float* Bp = B + (C0 + j0) + lc;
    float4 av = *reinterpret_cast<const float4*>(Ap + (size_t)lr * 4096);
    float4 bv = *reinterpret_cast<const float4*>(Bp + (size_t)lr * 4096);
    *reinterpret_cast<float4*>(&As[0][lr][lc]) = av;
    *reinterpret_cast<float4*>(&Bs[0][lr][lc]) = bv;
    for (int ct = 0; ct < 256; ct += 8) {
      const int buf = (ct >> 3) & 1;
      __syncthreads();
      if (ct + 8 < 256) {
        av = *reinterpret_cast<const float4*>(Ap + (size_t)(ct + 8 + lr) * 4096);
        bv = *reinterpret_cast<const float4*>(Bp + (size_t)(ct + 8 + lr) * 4096);
      }
      #pragma unroll
      for (int kc = 0; kc < 8; ++kc) {
        float a[8], b[8];
        *reinterpret_cast<float4*>(&a[0]) = *reinterpret_cast<const float4*>(&As[buf][kc][ty * 4]);
        *reinterpret_cast<float4*>(&a[4]) = *reinterpret_cast<const float4*>(&As[buf][kc][64 + ty * 4]);
        *reinterpret_cast<float4*>(&b[0]) = *reinterpret_cast<const float4*>(&Bs[buf][kc][tx * 4]);
        *reinterpret_cast<float4*>(&b[4]) = *reinterpret_cast<const float4*>(&Bs[buf][kc][64 + tx * 4]);
        #pragma unroll
        for (int i = 0; i < 8; ++i)
          #pragma unroll
          for (int j = 0; j < 8; ++j)
            acc[i][j] = fmaf(a[i], b[j], acc[i][j]);
      }
      if (ct + 8 < 256) {
        *reinterpret_cast<float4*>(&As[buf ^ 1][lr][lc]) = av;
        *reinterpret_cast<float4*>(&Bs[buf ^ 1][lr][lc]) = bv;
      }
    }
  }
  #pragma unroll
  for (int half = 0; half < 2; ++half)
    #pragma unroll
    for (int i = 0; i < 4; ++i) {
      float* Dp = D + (size_t)(k0 + half * 64 + ty * 4 + i) * ldD + j0;
      *reinterpret_cast<float4*>(Dp + tx * 4)      = *reinterpret_cast<const float4*>(&acc[half * 4 + i][0]);
      *reinterpret_cast<float4*>(Dp + 64 + tx * 4) = *reinterpret_cast<const float4*>(&acc[half * 4 + i][4]);
    }
}

// ---------------- tex0: LDS-staged gather, 4 channels interleaved ----------------
__global__ __launch_bounds__(256) void tex0_lds(const float* __restrict__ ref,
                                                const int* __restrict__ maxidx,
                                                float* __restrict__ outp) {
  __shared__ __align__(16) float4 L[4096];
  const int cq = blockIdx.x;
  const int n  = blockIdx.y;
  const int half = blockIdx.z;
  const int tid = threadIdx.x;
  const float* p0 = ref + (((size_t)n * 256 + cq * 4) << 12);
  for (int i = 0; i < 16; ++i) {
    int px = i * 256 + tid;
    L[px] = make_float4(p0[px], p0[px + 4096], p0[px + 8192], p0[px + 12288]);
  }
  __syncthreads();
  const int* mi = maxidx + n * 4096;
  float* ob = outp + (((size_t)n * 256 + cq * 4) << 12);
  for (int i = 0; i < 8; ++i) {
    int px = half * 2048 + i * 256 + tid;
    int y = px >> 6, x = px & 63;
    float ax = 0.f, ay = 0.f, az = 0.f, aw = 0.f;
    #pragma unroll
    for (int a = -1; a <= 1; ++a) {
      int jh = y + a;
      if ((unsigned)jh < 64u) {
        #pragma unroll
        for (int b = -1; b <= 1; ++b) {
          int jw = x + b;
          if ((unsigned)jw < 64u) {
            int m = mi[jh * 64 + jw];
            int rh = (m >> 6) - a;
            int cx = (m & 63) - b;
            if ((unsigned)rh < 64u && (unsigned)cx < 64u) {
              float4 v = L[rh * 64 + cx];
              ax += v.x; ay += v.y; az += v.z; aw += v.w;
            }
          }
        }
      }
    }
    ob[px]         = ax * (1.f / 9.f);
    ob[px + 4096]  = ay * (1.f / 9.f);
    ob[px + 8192]  = az * (1.f / 9.f);
    ob[px + 12288] = aw * (1.f / 9.f);
  }
}

// ---------------- tex1: LDS-staged gather, one 128x128 plane ----------------
__global__ __launch_bounds__(256) void tex1_lds(const float* __restrict__ ref,
                                                const int* __restrict__ maxidx,
                                                float* __restrict__ outp) {
  __shared__ __align__(16) float Lf[16384];
  const int c = blockIdx.x;
  const int n = blockIdx.y;
  const int half = blockIdx.z;
  const int tid = threadIdx.x;
  const float* p0 = ref + (((size_t)n * 128 + c) << 14);
  float4* L4 = (float4*)Lf;
  const float4* g4 = (const float4*)p0;
  for (int i = 0; i < 16; ++i) {
    int g = i * 256 + tid;
    L4[g] = g4[g];
  }
  __syncthreads();
  const int* mi = maxidx + n * 4096;
  float* ob = outp + (((size_t)n * 128 + c) << 14);
  for (int i = 0; i < 16; ++i) {
    int pp = half * 4096 + i * 256 + tid;
    int xp = pp & 63;
    int y  = pp >> 6;
    int jh0 = y >> 1;
    float a0 = 0.f, a1 = 0.f;
    #pragma unroll
    for (int a = -1; a <= 1; ++a) {
      int jh = jh0 + a;
      if ((unsigned)jh < 64u) {
        #pragma unroll
        for (int b = -1; b <= 1; ++b) {
          int jw = xp + b;
          if ((unsigned)jw < 64u) {
            int m = mi[jh * 64 + jw];
            int rh = (m >> 6) - a;
            int cx = (m & 63) - b;
            if ((unsigned)rh < 64u && (unsigned)cx < 64u) {
              int off = ((rh << 1) + (y & 1)) * 128 + (cx << 1);
              float2 v = *reinterpret_cast<const float2*>(&Lf[off]);
              a0 += v.x; a1 += v.y;
            }
          }
        }
      }
    }
    *reinterpret_cast<float2*>(&ob[y * 128 + xp * 2]) =
        make_float2(a0 * (1.f / 9.f), a1 * (1.f / 9.f));
  }
}

// ---------------- tex2: global float4 taps ----------------
__global__ __launch_bounds__(256) void tex2_k(const float* __restrict__ ref,
                                              const int* __restrict__ maxidx,
                                              float* __restrict__ outp) {
  int gid = blockIdx.x * 256 + threadIdx.x;
  const int xg = gid & 63;
  const int y  = (gid >> 6) & 255;
  const int cc = (gid >> 14) & 7;
  const int n  = gid >> 17;
  const int jh0 = y >> 2;
  const int* mi = maxidx + n * 4096;
  int offs[9];
  #pragma unroll
  for (int a = -1; a <= 1; ++a) {
    #pragma unroll
    for (int b = -1; b <= 1; ++b) {
      const int t = (a + 1) * 3 + (b + 1);
      int jh = jh0 + a, jw = xg + b;
      int off = -1;
      if ((unsigned)jh < 64u && (unsigned)jw < 64u) {
        int m = mi[jh * 64 + jw];
        int rh = (m >> 6) - jh + jh0;
        int cx = (m & 63) - jw + xg;
        if ((unsigned)rh < 64u && (unsigned)cx < 64u)
          off = ((rh << 2) + (y & 3)) * 256 + (cx << 2);
      }
      offs[t] = off;
    }
  }
  const float* rb = ref + (((size_t)n * 64 + cc * 8) << 16);
  float* ob = outp + ((((size_t)n * 64 + cc * 8) * 256 + y) << 8) + xg * 4;
  #pragma unroll
  for (int i = 0; i < 8; ++i) {
    const float* r = rb + ((size_t)i << 16);
    float4 acc = make_float4(0.f, 0.f, 0.f, 0.f);
    #pragma unroll
    for (int t = 0; t < 9; ++t) {
      if (offs[t] >= 0) {
        float4 v = *reinterpret_cast<const float4*>(r + offs[t]);
        acc.x += v.x; acc.y += v.y; acc.z += v.z; acc.w += v.w;
      }
    }
    acc.x *= (1.f / 9.f); acc.y *= (1.f / 9.f); acc.z *= (1.f / 9.f); acc.w *= (1.f / 9.f);
    *reinterpret_cast<float4*>(ob + ((size_t)i << 16)) = acc;
  }
}

// ---------------- launch ----------------
extern "C" void kernel_launch(void* const* d_in, const int* in_sizes, int n_in,
                              void* d_out, int out_size, void* d_ws, size_t ws_size,
                              hipStream_t stream) {
  const float* lq    = (const float*)d_in[0];
  const float* refdu = (const float*)d_in[1];
  const float* ref0  = (const float*)d_in[2];
  const float* ref1  = (const float*)d_in[3];
  const float* ref2  = (const float*)d_in[4];
  float* out = (float*)d_out;

  float* S      = (float*)d_ws;               // 16384
  float* qinv   = S + 16384;                  // 8192
  float* kinv   = qinv + 8192;                // 8192
  int*   maxidx = (int*)(kinv + 8192);        // 8192
  float* chunkv = (float*)(maxidx + 8192);    // 2*NCH*4096 = 2097152
  int*   chunki = (int*)(chunkv + 2097152);   // 2097152
  unsigned short* Ah = (unsigned short*)(chunki + 2097152);  // 2097152 ushorts each
  unsigned short* Al = Ah + 2097152;
  unsigned short* Bh = Al + 2097152;
  unsigned short* Bl = Bh + 2097152;
  const size_t aux_bytes = (size_t)(40960 + 2097152 + 2097152) * 4 + (size_t)4 * 2097152 * 2;
  float* D = (float*)((char*)d_ws + ((aux_bytes + 255) & ~(size_t)255));

  const int ldD = 4352;                        // q' in [-128, 4224)
  const size_t Dsz = (size_t)4096 * ldD * 4;   // 71.3 MB
  const long long dstr = (long long)4096 * ldD;
  size_t avail = (ws_size > aux_bytes + 256) ? (ws_size - aux_bytes - 256) : 0;

  sumsq_k<<<dim3(16, 2, 2), 256, 0, stream>>>(lq, refdu, S);
  norm_k<<<dim3(64), 256, 0, stream>>>(S, qinv, kinv);

  if (avail >= 2 * Dsz) {
    // merged MFMA path: both batches' D resident
    conv_t<<<dim3(64, 4, 2), 256, 0, stream>>>(refdu, Ah, Al);
    conv_t<<<dim3(64, 4, 2), 256, 0, stream>>>(lq, Bh, Bl);
    gemm_mfma<<<dim3(64, 68, 2), 256, 0, stream>>>(Ah, Al, Bh, Bl, D, ldD, -128, dstr);
    reduce_max8<<<dim3(2, NCH, 2), 256, 0, stream>>>(D, ldD, -128, 0, kinv,
                                                     chunkv, chunki, 0, dstr);
  } else if (avail >= Dsz) {
    conv_t<<<dim3(64, 4, 2), 256, 0, stream>>>(refdu, Ah, Al);
    conv_t<<<dim3(64, 4, 2), 256, 0, stream>>>(lq, Bh, Bl);
    for (int n = 0; n < 2; ++n) {
      gemm_mfma<<<dim3(64, 68, 1), 256, 0, stream>>>(
          Ah + (size_t)n * 1048576, Al + (size_t)n * 1048576,
          Bh + (size_t)n * 1048576, Bl + (size_t)n * 1048576, D, ldD, -128, 0);
      reduce_max8<<<dim3(2, NCH, 1), 256, 0, stream>>>(D, ldD, -128, 0, kinv,
                                                       chunkv, chunki, n, 0);
    }
  } else {
    // stripe fallback: fp32 gemm, halved-width D
    const int Wq = 2048, ldS = Wq + 256;
    for (int n = 0; n < 2; ++n) {
      for (int Q0 = 0; Q0 < 4096; Q0 += Wq) {
        int C0 = Q0 - 128;
        gemm_d<<<dim3(32, ldS / 128, 1), 256, 0, stream>>>(
            refdu + (size_t)n * 1048576, lq + (size_t)n * 1048576, D, ldS, C0, 0);
        reduce_max8<<<dim3(Wq / 2048, NCH, 1), 256, 0, stream>>>(
            D, ldS, C0, Q0, kinv, chunkv, chunki, n, 0);
      }
    }
  }
  combine_k<<<dim3(32), 256, 0, stream>>>(chunkv, chunki, qinv, out, maxidx, NCH);

  tex0_lds<<<dim3(64, 2, 2),  256, 0, stream>>>(ref0, maxidx, out + 8192);
  tex1_lds<<<dim3(128, 2, 2), 256, 0, stream>>>(ref1, maxidx, out + 2105344);
  tex2_k<<<dim3(1024), 256, 0, stream>>>(ref2, maxidx, out + 6299648);
}